// Round 4
// baseline (1052.561 us; speedup 1.0000x reference)
//
#include <hip/hip_runtime.h>
#include <hip/hip_bf16.h>
#include <math.h>

typedef __bf16 bf16;
typedef __bf16 bf16x4 __attribute__((ext_vector_type(4)));
typedef __bf16 bf16x8 __attribute__((ext_vector_type(8)));
typedef float  f32x4  __attribute__((ext_vector_type(4)));

#define T_TOK 4096
#define DIM   1024
#define NHEAD 16
#define SEQ   2048
#define NEXP  4
#define CAP   2048
#define MLPH  4096
#define MOEH  256

__device__ __forceinline__ float gelu_exact(float v) {
    return 0.5f * v * (1.f + erff(v * 0.70710678118654752f));
}

struct HL { bf16 h, l; };
__device__ __forceinline__ HL split2(float v) {
    HL r; r.h = (bf16)v; r.l = (bf16)(v - (float)r.h); return r;
}

// ---------------- transpose fp32 -> bf16 (32x32 tiles, batched in z) ----------------
__global__ __launch_bounds__(256)
void transpose_conv_kernel(const float* __restrict__ in, bf16* __restrict__ out, int R, int C) {
    __shared__ bf16 tile[32][33];
    long bo = (long)blockIdx.z * R * C;
    in += bo; out += bo;
    int c0 = blockIdx.x * 32, r0 = blockIdx.y * 32;
    int tx = threadIdx.x & 31, ty = threadIdx.x >> 5; // 32 x 8 threads
    #pragma unroll
    for (int i = 0; i < 32; i += 8)
        tile[ty + i][tx] = (bf16)in[(long)(r0 + ty + i) * C + c0 + tx];
    __syncthreads();
    #pragma unroll
    for (int i = 0; i < 32; i += 8)
        out[(long)(c0 + ty + i) * R + r0 + tx] = tile[tx][ty + i];
}

// ---------------- LayerNorm (fp32 in, fp32 or bf16 out): one wave per token ----------------
template<typename TOUT>
__global__ __launch_bounds__(256)
void ln_kernel(const float* __restrict__ x, const float* __restrict__ g,
               const float* __restrict__ b, TOUT* __restrict__ out) {
    int wave = threadIdx.x >> 6, lane = threadIdx.x & 63;
    long t = (long)blockIdx.x * 4 + wave;
    const float* xr = x + t * DIM;
    float v[16];
    #pragma unroll
    for (int i = 0; i < 16; i++) v[i] = xr[i * 64 + lane];
    float s = 0.f, s2 = 0.f;
    #pragma unroll
    for (int i = 0; i < 16; i++) { s += v[i]; s2 += v[i] * v[i]; }
    #pragma unroll
    for (int m = 1; m < 64; m <<= 1) { s += __shfl_xor(s, m); s2 += __shfl_xor(s2, m); }
    float mu  = s * (1.f / DIM);
    float var = s2 * (1.f / DIM) - mu * mu;
    float rs  = 1.f / sqrtf(var + 1e-5f);
    TOUT* orow = out + t * DIM;
    #pragma unroll
    for (int i = 0; i < 16; i++) {
        int d = i * 64 + lane;
        orow[d] = (TOUT)((v[i] - mu) * rs * g[d] + b[d]);
    }
}

// ---------------- fp32-faithful split-bf16 GEMM: C = A @ Bt^T (+bias) (+res) ----------------
// A (M,K) fp32 row-major, Bt (N,K) fp32 row-major, C fp32.
template<bool BIAS, bool RESID>
__global__ __launch_bounds__(256)
void gemm_f32split(const float* __restrict__ A, const float* __restrict__ Bt,
                   const float* __restrict__ bias, const float* __restrict__ res,
                   float* __restrict__ C, int M, int N, int K) {
    __shared__ alignas(16) bf16 Ah[128][72], Al[128][72], Bh[128][72], Bl[128][72];
    int tid = threadIdx.x;
    int wave = tid >> 6, lane = tid & 63;
    int l16 = lane & 15, l4 = lane >> 4;
    int wr = (wave >> 1) * 64, wc = (wave & 1) * 64;
    int row0 = blockIdx.y * 128, col0 = blockIdx.x * 128;
    f32x4 acc[4][4] = {};
    for (int k0 = 0; k0 < K; k0 += 64) {
        #pragma unroll
        for (int p = 0; p < 8; p++) {
            int f4 = p * 256 + tid;
            int r = f4 >> 4, c = (f4 & 15) * 4;
            f32x4 va = *(const f32x4*)&A[(long)(row0 + r) * K + k0 + c];
            f32x4 vb = *(const f32x4*)&Bt[(long)(col0 + r) * K + k0 + c];
            bf16x4 ha, la, hb, lb;
            #pragma unroll
            for (int j = 0; j < 4; j++) {
                HL sa = split2(va[j]); ha[j] = sa.h; la[j] = sa.l;
                HL sb = split2(vb[j]); hb[j] = sb.h; lb[j] = sb.l;
            }
            *(bf16x4*)&Ah[r][c] = ha; *(bf16x4*)&Al[r][c] = la;
            *(bf16x4*)&Bh[r][c] = hb; *(bf16x4*)&Bl[r][c] = lb;
        }
        __syncthreads();
        #pragma unroll
        for (int ks = 0; ks < 2; ks++) {
            bf16x8 ah[4], al[4], bh[4], bl[4];
            #pragma unroll
            for (int i = 0; i < 4; i++) {
                ah[i] = *(const bf16x8*)&Ah[wr + i*16 + l16][ks*32 + l4*8];
                al[i] = *(const bf16x8*)&Al[wr + i*16 + l16][ks*32 + l4*8];
            }
            #pragma unroll
            for (int j = 0; j < 4; j++) {
                bh[j] = *(const bf16x8*)&Bh[wc + j*16 + l16][ks*32 + l4*8];
                bl[j] = *(const bf16x8*)&Bl[wc + j*16 + l16][ks*32 + l4*8];
            }
            #pragma unroll
            for (int i = 0; i < 4; i++)
                #pragma unroll
                for (int j = 0; j < 4; j++) {
                    acc[i][j] = __builtin_amdgcn_mfma_f32_16x16x32_bf16(ah[i], bh[j], acc[i][j], 0, 0, 0);
                    acc[i][j] = __builtin_amdgcn_mfma_f32_16x16x32_bf16(ah[i], bl[j], acc[i][j], 0, 0, 0);
                    acc[i][j] = __builtin_amdgcn_mfma_f32_16x16x32_bf16(al[i], bh[j], acc[i][j], 0, 0, 0);
                }
        }
        __syncthreads();
    }
    #pragma unroll
    for (int i = 0; i < 4; i++)
        #pragma unroll
        for (int r = 0; r < 4; r++) {
            int grow = row0 + wr + i * 16 + l4 * 4 + r;
            #pragma unroll
            for (int j = 0; j < 4; j++) {
                int gcol = col0 + wc + j * 16 + l16;
                float v = acc[i][j][r];
                if (BIAS)  v += bias[gcol];
                if (RESID) v += res[(long)grow * N + gcol];
                C[(long)grow * N + gcol] = v;
            }
        }
}

// ---------------- plain bf16 GEMM (post-decision paths): C = act(A @ Bt^T + bias) ----------------
// OUT_MODE 0: bf16 store; 2: fp32 += v; 3: atomicAdd(Cf[rowmap[row]*N+col], roww[row]*v)
template<bool BIAS, bool GELU, bool GATHER, int OUT_MODE>
__global__ __launch_bounds__(256)
void gemm_bt(const bf16* __restrict__ A, const bf16* __restrict__ Bt,
             const float* __restrict__ bias,
             bf16* __restrict__ Cbf, float* __restrict__ Cf,
             const int* __restrict__ rowmap, const float* __restrict__ roww,
             int M, int N, int K) {
    __shared__ alignas(16) bf16 As[128][72];
    __shared__ alignas(16) bf16 Bs[128][72];
    int tid = threadIdx.x;
    int wave = tid >> 6, lane = tid & 63;
    int l16 = lane & 15, l4 = lane >> 4;
    int wr = (wave >> 1) * 64, wc = (wave & 1) * 64;
    int row0 = blockIdx.y * 128, col0 = blockIdx.x * 128;

    int sr[4], sc[4]; long arow[4];
    #pragma unroll
    for (int p = 0; p < 4; p++) {
        int idx = p * 2048 + tid * 8;
        sr[p] = idx >> 6; sc[p] = idx & 63;
        long gr = row0 + sr[p];
        if (GATHER) gr = rowmap[gr];
        arow[p] = gr;
    }
    f32x4 acc[4][4] = {};
    for (int k0 = 0; k0 < K; k0 += 64) {
        #pragma unroll
        for (int p = 0; p < 4; p++) {
            *(bf16x8*)&As[sr[p]][sc[p]] = *(const bf16x8*)&A[arow[p] * K + k0 + sc[p]];
            *(bf16x8*)&Bs[sr[p]][sc[p]] = *(const bf16x8*)&Bt[(long)(col0 + sr[p]) * K + k0 + sc[p]];
        }
        __syncthreads();
        #pragma unroll
        for (int ks = 0; ks < 2; ks++) {
            bf16x8 af[4], bfr[4];
            #pragma unroll
            for (int i = 0; i < 4; i++) af[i]  = *(const bf16x8*)&As[wr + i*16 + l16][ks*32 + l4*8];
            #pragma unroll
            for (int j = 0; j < 4; j++) bfr[j] = *(const bf16x8*)&Bs[wc + j*16 + l16][ks*32 + l4*8];
            #pragma unroll
            for (int i = 0; i < 4; i++)
                #pragma unroll
                for (int j = 0; j < 4; j++)
                    acc[i][j] = __builtin_amdgcn_mfma_f32_16x16x32_bf16(af[i], bfr[j], acc[i][j], 0, 0, 0);
        }
        __syncthreads();
    }
    #pragma unroll
    for (int i = 0; i < 4; i++)
        #pragma unroll
        for (int r = 0; r < 4; r++) {
            int grow = row0 + wr + i * 16 + l4 * 4 + r;
            int st = 0; float sw = 0.f;
            if (OUT_MODE == 3) { st = rowmap[grow]; sw = roww[grow]; }
            #pragma unroll
            for (int j = 0; j < 4; j++) {
                int gcol = col0 + wc + j * 16 + l16;
                float v = acc[i][j][r];
                if (BIAS) v += bias[gcol];
                if (GELU) v = gelu_exact(v);
                if (OUT_MODE == 0) {
                    Cbf[(long)grow * N + gcol] = (bf16)v;
                } else if (OUT_MODE == 2) {
                    long o = (long)grow * N + gcol;
                    Cf[o] += v;
                } else {
                    atomicAdd(&Cf[(long)st * N + gcol], sw * v);
                }
            }
        }
}

// ---------------- flash attention, fp32-faithful via split-bf16 MFMA ----------------
__global__ __launch_bounds__(256)
void flash_attn(const float* __restrict__ qkv, float* __restrict__ ao) {
    __shared__ alignas(16) bf16 Qh[64][72], Ql[64][72], Kh[64][72], Kl[64][72];
    __shared__ alignas(16) bf16 Vth[64][72], Vtl[64][72];
    __shared__ alignas(16) bf16 Ph[4][16][72], Pl[4][16][72];
    int tid = threadIdx.x;
    int wave = tid >> 6, lane = tid & 63;
    int l16 = lane & 15, l4 = lane >> 4;
    int bh = blockIdx.y;
    int b = bh >> 4, h = bh & 15;
    int q0 = blockIdx.x * 64;
    const long rstride = 3 * DIM;
    const float* qbase = qkv + (long)b * SEQ * rstride + h * 64;
    const float* kbase = qbase + DIM;
    const float* vbase = qbase + 2 * DIM;

    // stage Q (64x64 fp32 -> hi/lo)
    #pragma unroll
    for (int p = 0; p < 4; p++) {
        int f4 = p * 256 + tid;
        int r = f4 >> 4, c = (f4 & 15) * 4;
        f32x4 v = *(const f32x4*)&qbase[(long)(q0 + r) * rstride + c];
        bf16x4 hh, ll;
        #pragma unroll
        for (int j = 0; j < 4; j++) { HL sv = split2(v[j]); hh[j] = sv.h; ll[j] = sv.l; }
        *(bf16x4*)&Qh[r][c] = hh; *(bf16x4*)&Ql[r][c] = ll;
    }
    float m_r[4], l_r[4];
    f32x4 accO[4] = {};
    #pragma unroll
    for (int r = 0; r < 4; r++) { m_r[r] = -1e30f; l_r[r] = 0.f; }

    for (int c0 = 0; c0 < SEQ; c0 += 64) {
        __syncthreads();   // prev iter's LDS reads done (covers Q staging on iter 0)
        #pragma unroll
        for (int p = 0; p < 4; p++) {
            int f4 = p * 256 + tid;
            int r = f4 >> 4, c = (f4 & 15) * 4;
            f32x4 kv = *(const f32x4*)&kbase[(long)(c0 + r) * rstride + c];
            f32x4 vv = *(const f32x4*)&vbase[(long)(c0 + r) * rstride + c];
            bf16x4 hh, ll;
            #pragma unroll
            for (int j = 0; j < 4; j++) { HL sk = split2(kv[j]); hh[j] = sk.h; ll[j] = sk.l; }
            *(bf16x4*)&Kh[r][c] = hh; *(bf16x4*)&Kl[r][c] = ll;
            #pragma unroll
            for (int j = 0; j < 4; j++) {
                HL sv = split2(vv[j]);
                Vth[c + j][r] = sv.h; Vtl[c + j][r] = sv.l;   // transposed: Vt[d][key]
            }
        }
        __syncthreads();
        // S = (1/8) * Q K^T for rows [wave*16,+16), cols [0,64)
        f32x4 s[4] = {};
        #pragma unroll
        for (int ks = 0; ks < 2; ks++) {
            bf16x8 aqh = *(const bf16x8*)&Qh[wave * 16 + l16][ks * 32 + l4 * 8];
            bf16x8 aql = *(const bf16x8*)&Ql[wave * 16 + l16][ks * 32 + l4 * 8];
            #pragma unroll
            for (int j = 0; j < 4; j++) {
                bf16x8 bkh = *(const bf16x8*)&Kh[j * 16 + l16][ks * 32 + l4 * 8];
                bf16x8 bkl = *(const bf16x8*)&Kl[j * 16 + l16][ks * 32 + l4 * 8];
                s[j] = __builtin_amdgcn_mfma_f32_16x16x32_bf16(aqh, bkh, s[j], 0, 0, 0);
                s[j] = __builtin_amdgcn_mfma_f32_16x16x32_bf16(aqh, bkl, s[j], 0, 0, 0);
                s[j] = __builtin_amdgcn_mfma_f32_16x16x32_bf16(aql, bkh, s[j], 0, 0, 0);
            }
        }
        #pragma unroll
        for (int j = 0; j < 4; j++)
            #pragma unroll
            for (int r = 0; r < 4; r++) s[j][r] *= 0.125f;
        // online softmax; lane's register r owns local row l4*4+r
        #pragma unroll
        for (int r = 0; r < 4; r++) {
            float mx = fmaxf(fmaxf(s[0][r], s[1][r]), fmaxf(s[2][r], s[3][r]));
            #pragma unroll
            for (int m = 1; m < 16; m <<= 1) mx = fmaxf(mx, __shfl_xor(mx, m));
            float mnew = fmaxf(m_r[r], mx);
            float alpha = expf(m_r[r] - mnew);
            float psum = 0.f;
            #pragma unroll
            for (int j = 0; j < 4; j++) {
                float pv = expf(s[j][r] - mnew);
                s[j][r] = pv; psum += pv;
            }
            #pragma unroll
            for (int m = 1; m < 16; m <<= 1) psum += __shfl_xor(psum, m);
            l_r[r] = l_r[r] * alpha + psum;
            m_r[r] = mnew;
            #pragma unroll
            for (int j = 0; j < 4; j++) accO[j][r] *= alpha;
        }
        // P (fp32) -> hi/lo bf16 in per-wave LDS (C-layout -> A-layout round trip)
        #pragma unroll
        for (int j = 0; j < 4; j++)
            #pragma unroll
            for (int r = 0; r < 4; r++) {
                HL sp = split2(s[j][r]);
                Ph[wave][l4 * 4 + r][j * 16 + l16] = sp.h;
                Pl[wave][l4 * 4 + r][j * 16 + l16] = sp.l;
            }
        // O += P @ V
        #pragma unroll
        for (int ks = 0; ks < 2; ks++) {
            bf16x8 aph = *(const bf16x8*)&Ph[wave][l16][ks * 32 + l4 * 8];
            bf16x8 apl = *(const bf16x8*)&Pl[wave][l16][ks * 32 + l4 * 8];
            #pragma unroll
            for (int j = 0; j < 4; j++) {
                bf16x8 bvh = *(const bf16x8*)&Vth[j * 16 + l16][ks * 32 + l4 * 8];
                bf16x8 bvl = *(const bf16x8*)&Vtl[j * 16 + l16][ks * 32 + l4 * 8];
                accO[j] = __builtin_amdgcn_mfma_f32_16x16x32_bf16(aph, bvh, accO[j], 0, 0, 0);
                accO[j] = __builtin_amdgcn_mfma_f32_16x16x32_bf16(aph, bvl, accO[j], 0, 0, 0);
                accO[j] = __builtin_amdgcn_mfma_f32_16x16x32_bf16(apl, bvh, accO[j], 0, 0, 0);
            }
        }
    }
    #pragma unroll
    for (int j = 0; j < 4; j++)
        #pragma unroll
        for (int r = 0; r < 4; r++) {
            int grow = q0 + wave * 16 + l4 * 4 + r;
            ao[((long)(b * SEQ + grow)) * DIM + h * 64 + j * 16 + l16] = accO[j][r] / l_r[r];
        }
}

// ---------------- routing (pure fp32, LN inline): one wave per token ----------------
__global__ __launch_bounds__(256)
void routing_kernel(const float* __restrict__ xres, const float* __restrict__ g,
                    const float* __restrict__ b, const float* __restrict__ w_route,
                    const float* __restrict__ b_route, const float* __restrict__ w_noise,
                    const float* __restrict__ b_noise, const float* __restrict__ noise,
                    int* __restrict__ topi, float* __restrict__ topp) {
    int wave = threadIdx.x >> 6, lane = threadIdx.x & 63;
    long t = (long)blockIdx.x * 4 + wave;
    const float* xr = xres + t * DIM;
    float v[16];
    #pragma unroll
    for (int i = 0; i < 16; i++) v[i] = xr[i * 64 + lane];
    float s = 0.f, s2 = 0.f;
    #pragma unroll
    for (int i = 0; i < 16; i++) { s += v[i]; s2 += v[i] * v[i]; }
    #pragma unroll
    for (int m = 1; m < 64; m <<= 1) { s += __shfl_xor(s, m); s2 += __shfl_xor(s2, m); }
    float mu  = s * (1.f / DIM);
    float var = s2 * (1.f / DIM) - mu * mu;
    float rs  = 1.f / sqrtf(var + 1e-5f);
    float accr[4] = {0.f,0.f,0.f,0.f}, accn[4] = {0.f,0.f,0.f,0.f};
    #pragma unroll
    for (int i = 0; i < 16; i++) {
        int d = i * 64 + lane;
        float n = (v[i] - mu) * rs * g[d] + b[d];
        #pragma unroll
        for (int e = 0; e < 4; e++) {
            accr[e] += n * w_route[d * 4 + e];
            accn[e] += n * w_noise[d * 4 + e];
        }
    }
    #pragma unroll
    for (int e = 0; e < 4; e++)
        #pragma unroll
        for (int m = 1; m < 64; m <<= 1) {
            accr[e] += __shfl_xor(accr[e], m);
            accn[e] += __shfl_xor(accn[e], m);
        }
    if (lane == 0) {
        float nz[4];
        #pragma unroll
        for (int e = 0; e < 4; e++) {
            float logit = accr[e] + b_route[e];
            float si = accn[e] + b_noise[e];
            float sp = si > 0.f ? si + log1pf(expf(-si)) : log1pf(expf(si)); // softplus
            nz[e] = logit + noise[t * 4 + e] * sp;
        }
        int i1 = 0;
        #pragma unroll
        for (int e = 1; e < 4; e++) if (nz[e] > nz[i1]) i1 = e;   // strict >: lower idx wins ties
        int i2 = -1; float v2 = -1e30f;
        #pragma unroll
        for (int e = 0; e < 4; e++) if (e != i1 && nz[e] > v2) { v2 = nz[e]; i2 = e; }
        float ex = expf(v2 - nz[i1]);                              // softmax over top-2
        topi[t * 2]     = i1; topi[t * 2 + 1] = i2;
        topp[t * 2]     = 1.f / (1.f + ex);
        topp[t * 2 + 1] = ex / (1.f + ex);
    }
}

// ---------------- dispatch: per-expert ordered token lists (wave e = expert e) ----------------
__global__ __launch_bounds__(256)
void dispatch_kernel(const int* __restrict__ topi, const float* __restrict__ topp,
                     int* __restrict__ sel, float* __restrict__ wgt) {
    int e = threadIdx.x >> 6, lane = threadIdx.x & 63;
    int cnt = 0;
    for (int c = 0; c < T_TOK; c += 64) {
        int t = c + lane;
        int i0 = topi[t * 2], i1 = topi[t * 2 + 1];
        bool m = (i0 == e) || (i1 == e);
        unsigned long long bal = __ballot(m);
        int pos = cnt + __popcll(bal & ((1ull << lane) - 1ull));
        if (m && pos < CAP) {
            sel[e * CAP + pos] = t;
            wgt[e * CAP + pos] = (i0 == e) ? topp[t * 2] : topp[t * 2 + 1];
        }
        cnt += (int)__popcll(bal);
    }
    if (cnt > CAP) cnt = CAP;
    for (int pos = cnt + lane; pos < CAP; pos += 64) {  // unfilled slots: token 0, weight 0
        sel[e * CAP + pos] = 0;
        wgt[e * CAP + pos] = 0.f;
    }
}

// ---------------- final fp32 copy ----------------
__global__ __launch_bounds__(256)
void out_copy_kernel(const float* __restrict__ in, float* __restrict__ out) {
    long i0 = ((long)blockIdx.x * 256 + threadIdx.x) * 4;
    *(f32x4*)&out[i0] = *(const f32x4*)&in[i0];
}

extern "C" void kernel_launch(void* const* d_in, const int* in_sizes, int n_in,
                              void* d_out, int out_size, void* d_ws, size_t ws_size,
                              hipStream_t stream) {
    (void)in_sizes; (void)n_in; (void)out_size; (void)ws_size;
    const float* x       = (const float*)d_in[0];
    const float* noise   = (const float*)d_in[1];
    const float* ln1_g   = (const float*)d_in[2];
    const float* ln1_b   = (const float*)d_in[3];
    const float* ln2_g   = (const float*)d_in[4];
    const float* ln2_b   = (const float*)d_in[5];
    const float* w_qkv   = (const float*)d_in[6];
    const float* w_proj  = (const float*)d_in[7];
    const float* b_proj  = (const float*)d_in[8];
    const float* w_route = (const float*)d_in[9];
    const float* b_route = (const float*)d_in[10];
    const float* w_noise = (const float*)d_in[11];
    const float* b_noise = (const float*)d_in[12];
    const float* we1     = (const float*)d_in[13];
    const float* be1     = (const float*)d_in[14];
    const float* we2     = (const float*)d_in[15];
    const float* be2     = (const float*)d_in[16];
    const float* w_mlp1  = (const float*)d_in[17];
    const float* b_mlp1  = (const float*)d_in[18];
    const float* w_mlp2  = (const float*)d_in[19];
    const float* b_mlp2  = (const float*)d_in[20];

    // ---- workspace layout (~92.5 MB) ----
    char* p = (char*)d_ws;
    // region A (50.33 MB): qkvf fp32 during attention; then h_mlp + w_mlp transposes
    char* regionA = p;        p += (size_t)T_TOK * 3 * DIM * 4;
    float* qkvf   = (float*)regionA;
    bf16*  h_mlp  = (bf16*)regionA;                                       // 33.55 MB
    bf16*  w_mlp1T = (bf16*)(regionA + (size_t)T_TOK * MLPH * 2);         // 8.39 MB
    bf16*  w_mlp2T = (bf16*)(regionA + (size_t)T_TOK * MLPH * 2 + (size_t)MLPH * DIM * 2);
    // region B (16.78 MB): x1f fp32 -> aof fp32 -> h_e + we1T + we2T
    char* regionB = p;        p += (size_t)T_TOK * DIM * 4;
    float* x1f  = (float*)regionB;
    float* aof  = (float*)regionB;
    bf16*  h_e  = (bf16*)regionB;                                         // 4.19 MB
    bf16*  we1T = (bf16*)(regionB + (size_t)NEXP * CAP * MOEH * 2);       // 2.10 MB
    bf16*  we2T = (bf16*)(regionB + (size_t)NEXP * CAP * MOEH * 2 + (size_t)NEXP * MOEH * DIM * 2);
    float* x_res = (float*)p; p += (size_t)T_TOK * DIM * 4;               // 16.78 MB
    bf16*  x2b   = (bf16*)p;  p += (size_t)T_TOK * DIM * 2;               // 8.39 MB
    int*   topi  = (int*)p;   p += (size_t)T_TOK * 2 * 4;
    float* topp  = (float*)p; p += (size_t)T_TOK * 2 * 4;
    int*   sel   = (int*)p;   p += (size_t)NEXP * CAP * 4;
    float* wgt   = (float*)p; p += (size_t)NEXP * CAP * 4;

    // ---- LN1 -> QKV(split) -> attention(split) -> proj(split, +bias+residual) ----
    ln_kernel<float><<<T_TOK/4, 256, 0, stream>>>(x, ln1_g, ln1_b, x1f);
    gemm_f32split<false,false><<<dim3(3*DIM/128, T_TOK/128), 256, 0, stream>>>(
        x1f, w_qkv, nullptr, nullptr, qkvf, T_TOK, 3*DIM, DIM);
    flash_attn<<<dim3(SEQ/64, 2*NHEAD), 256, 0, stream>>>(qkvf, aof);
    gemm_f32split<true,true><<<dim3(DIM/128, T_TOK/128), 256, 0, stream>>>(
        aof, w_proj, b_proj, x, x_res, T_TOK, DIM, DIM);

    // ---- LN2 (bf16 for compute paths) + routing (fp32, LN inline) -> dispatch ----
    ln_kernel<bf16><<<T_TOK/4, 256, 0, stream>>>(x_res, ln2_g, ln2_b, x2b);
    routing_kernel<<<T_TOK/4, 256, 0, stream>>>(x_res, ln2_g, ln2_b, w_route, b_route,
                                                w_noise, b_noise, noise, topi, topp);
    dispatch_kernel<<<1, 256, 0, stream>>>(topi, topp, sel, wgt);

    // ---- weight transposes (fp32 -> bf16, k-contiguous); regions A/B now free ----
    transpose_conv_kernel<<<dim3(MLPH/32, DIM/32, 1),    256, 0, stream>>>(w_mlp1, w_mlp1T, DIM, MLPH);
    transpose_conv_kernel<<<dim3(DIM/32, MLPH/32, 1),    256, 0, stream>>>(w_mlp2, w_mlp2T, MLPH, DIM);
    transpose_conv_kernel<<<dim3(MOEH/32, DIM/32, NEXP), 256, 0, stream>>>(we1, we1T, DIM, MOEH);
    transpose_conv_kernel<<<dim3(DIM/32, MOEH/32, NEXP), 256, 0, stream>>>(we2, we2T, MOEH, DIM);

    // ---- dense MLP ----
    gemm_bt<true,true,false,0><<<dim3(MLPH/128, T_TOK/128), 256, 0, stream>>>(
        x2b, w_mlp1T, b_mlp1, h_mlp, nullptr, nullptr, nullptr, T_TOK, MLPH, DIM);
    gemm_bt<true,false,false,2><<<dim3(DIM/128, T_TOK/128), 256, 0, stream>>>(
        h_mlp, w_mlp2T, b_mlp2, nullptr, x_res, nullptr, nullptr, T_TOK, DIM, MLPH);

    // ---- MoE experts: gather -> GEMM+GELU -> GEMM -> gated atomic scatter ----
    for (int e = 0; e < NEXP; e++) {
        gemm_bt<true,true,true,0><<<dim3(MOEH/128, CAP/128), 256, 0, stream>>>(
            x2b, we1T + (size_t)e*MOEH*DIM, be1 + e*MOEH, h_e + (size_t)e*CAP*MOEH,
            nullptr, sel + e*CAP, nullptr, CAP, MOEH, DIM);
    }
    for (int e = 0; e < NEXP; e++) {
        gemm_bt<true,false,false,3><<<dim3(DIM/128, CAP/128), 256, 0, stream>>>(
            h_e + (size_t)e*CAP*MOEH, we2T + (size_t)e*DIM*MOEH, be2 + e*DIM,
            nullptr, x_res, sel + e*CAP, wgt + e*CAP, CAP, DIM, MOEH);
    }

    out_copy_kernel<<<(T_TOK*DIM)/(256*4), 256, 0, stream>>>(x_res, (float*)d_out);
}

// Round 5
// 985.139 us; speedup vs baseline: 1.0684x; 1.0684x over previous
//
#include <hip/hip_runtime.h>
#include <hip/hip_bf16.h>
#include <math.h>

typedef __bf16 bf16;
typedef __bf16 bf16x4 __attribute__((ext_vector_type(4)));
typedef __bf16 bf16x8 __attribute__((ext_vector_type(8)));
typedef float  f32x4  __attribute__((ext_vector_type(4)));

#define T_TOK 4096
#define DIM   1024
#define NHEAD 16
#define SEQ   2048
#define NEXP  4
#define CAP   2048
#define MLPH  4096
#define MOEH  256

__device__ __forceinline__ float gelu_exact(float v) {
    return 0.5f * v * (1.f + erff(v * 0.70710678118654752f));
}

struct HL { bf16 h, l; };
__device__ __forceinline__ HL split2(float v) {
    HL r; r.h = (bf16)v; r.l = (bf16)(v - (float)r.h); return r;
}

// ---------------- LN1 -> hi/lo bf16 planes: one wave per token ----------------
__global__ __launch_bounds__(256)
void ln_split_kernel(const float* __restrict__ x, const float* __restrict__ g,
                     const float* __restrict__ b, bf16* __restrict__ oh, bf16* __restrict__ ol) {
    int wave = threadIdx.x >> 6, lane = threadIdx.x & 63;
    long t = (long)blockIdx.x * 4 + wave;
    const float* xr = x + t * DIM;
    float v[16];
    #pragma unroll
    for (int i = 0; i < 16; i++) v[i] = xr[i * 64 + lane];
    float s = 0.f, s2 = 0.f;
    #pragma unroll
    for (int i = 0; i < 16; i++) { s += v[i]; s2 += v[i] * v[i]; }
    #pragma unroll
    for (int m = 1; m < 64; m <<= 1) { s += __shfl_xor(s, m); s2 += __shfl_xor(s2, m); }
    float mu  = s * (1.f / DIM);
    float var = s2 * (1.f / DIM) - mu * mu;
    float rs  = 1.f / sqrtf(var + 1e-5f);
    #pragma unroll
    for (int i = 0; i < 16; i++) {
        int d = i * 64 + lane;
        HL sp = split2((v[i] - mu) * rs * g[d] + b[d]);
        oh[t * DIM + d] = sp.h; ol[t * DIM + d] = sp.l;
    }
}

// ---------------- LN (fp32 in -> bf16 out): one wave per token ----------------
__global__ __launch_bounds__(256)
void ln_kernel(const float* __restrict__ x, const float* __restrict__ g,
               const float* __restrict__ b, bf16* __restrict__ out) {
    int wave = threadIdx.x >> 6, lane = threadIdx.x & 63;
    long t = (long)blockIdx.x * 4 + wave;
    const float* xr = x + t * DIM;
    float v[16];
    #pragma unroll
    for (int i = 0; i < 16; i++) v[i] = xr[i * 64 + lane];
    float s = 0.f, s2 = 0.f;
    #pragma unroll
    for (int i = 0; i < 16; i++) { s += v[i]; s2 += v[i] * v[i]; }
    #pragma unroll
    for (int m = 1; m < 64; m <<= 1) { s += __shfl_xor(s, m); s2 += __shfl_xor(s2, m); }
    float mu  = s * (1.f / DIM);
    float var = s2 * (1.f / DIM) - mu * mu;
    float rs  = 1.f / sqrtf(var + 1e-5f);
    #pragma unroll
    for (int i = 0; i < 16; i++) {
        int d = i * 64 + lane;
        out[t * DIM + d] = (bf16)((v[i] - mu) * rs * g[d] + b[d]);
    }
}

// ---------------- elementwise fp32 -> hi/lo planes ----------------
__global__ __launch_bounds__(256)
void split_pair_kernel(const float* __restrict__ in, bf16* __restrict__ h, bf16* __restrict__ l) {
    long i0 = ((long)blockIdx.x * 256 + threadIdx.x) * 4;
    f32x4 v = *(const f32x4*)&in[i0];
    bf16x4 vh, vl;
    #pragma unroll
    for (int j = 0; j < 4; j++) { HL sp = split2(v[j]); vh[j] = sp.h; vl[j] = sp.l; }
    *(bf16x4*)&h[i0] = vh; *(bf16x4*)&l[i0] = vl;
}

// ---------------- transpose fp32 -> bf16 (32x32 tiles, batched in z) ----------------
__global__ __launch_bounds__(256)
void transpose_conv_kernel(const float* __restrict__ in, bf16* __restrict__ out, int R, int C) {
    __shared__ bf16 tile[32][33];
    long bo = (long)blockIdx.z * R * C;
    in += bo; out += bo;
    int c0 = blockIdx.x * 32, r0 = blockIdx.y * 32;
    int tx = threadIdx.x & 31, ty = threadIdx.x >> 5;
    #pragma unroll
    for (int i = 0; i < 32; i += 8)
        tile[ty + i][tx] = (bf16)in[(long)(r0 + ty + i) * C + c0 + tx];
    __syncthreads();
    #pragma unroll
    for (int i = 0; i < 32; i += 8)
        out[(long)(c0 + ty + i) * R + r0 + tx] = tile[tx][ty + i];
}

// ---------------- qkv GEMM (pre-split inputs), epilogue routes Q/K->fp32, V->split Vt ----------------
__global__ __launch_bounds__(256)
void gemm_qkv(const bf16* __restrict__ Ah_g, const bf16* __restrict__ Al_g,
              const bf16* __restrict__ Bh_g, const bf16* __restrict__ Bl_g,
              float* __restrict__ qkvQK, bf16* __restrict__ VtH, bf16* __restrict__ VtL) {
    const int K = DIM;
    __shared__ alignas(16) bf16 Ah[128][72], Al[128][72], Bh[128][72], Bl[128][72];
    int tid = threadIdx.x;
    int wave = tid >> 6, lane = tid & 63;
    int l16 = lane & 15, l4 = lane >> 4;
    int wr = (wave >> 1) * 64, wc = (wave & 1) * 64;
    int row0 = blockIdx.y * 128, col0 = blockIdx.x * 128;
    f32x4 acc[4][4] = {};
    for (int k0 = 0; k0 < K; k0 += 64) {
        #pragma unroll
        for (int p = 0; p < 4; p++) {
            int idx = p * 2048 + tid * 8; int r = idx >> 6, c = idx & 63;
            *(bf16x8*)&Ah[r][c] = *(const bf16x8*)&Ah_g[(long)(row0 + r) * K + k0 + c];
            *(bf16x8*)&Al[r][c] = *(const bf16x8*)&Al_g[(long)(row0 + r) * K + k0 + c];
            *(bf16x8*)&Bh[r][c] = *(const bf16x8*)&Bh_g[(long)(col0 + r) * K + k0 + c];
            *(bf16x8*)&Bl[r][c] = *(const bf16x8*)&Bl_g[(long)(col0 + r) * K + k0 + c];
        }
        __syncthreads();
        #pragma unroll
        for (int ks = 0; ks < 2; ks++) {
            bf16x8 ah[4], al[4], bh[4], bl[4];
            #pragma unroll
            for (int i = 0; i < 4; i++) {
                ah[i] = *(const bf16x8*)&Ah[wr + i*16 + l16][ks*32 + l4*8];
                al[i] = *(const bf16x8*)&Al[wr + i*16 + l16][ks*32 + l4*8];
            }
            #pragma unroll
            for (int j = 0; j < 4; j++) {
                bh[j] = *(const bf16x8*)&Bh[wc + j*16 + l16][ks*32 + l4*8];
                bl[j] = *(const bf16x8*)&Bl[wc + j*16 + l16][ks*32 + l4*8];
            }
            #pragma unroll
            for (int i = 0; i < 4; i++)
                #pragma unroll
                for (int j = 0; j < 4; j++) {
                    acc[i][j] = __builtin_amdgcn_mfma_f32_16x16x32_bf16(ah[i], bh[j], acc[i][j], 0, 0, 0);
                    acc[i][j] = __builtin_amdgcn_mfma_f32_16x16x32_bf16(ah[i], bl[j], acc[i][j], 0, 0, 0);
                    acc[i][j] = __builtin_amdgcn_mfma_f32_16x16x32_bf16(al[i], bh[j], acc[i][j], 0, 0, 0);
                }
        }
        __syncthreads();
    }
    if (col0 < 2048) {   // Q/K columns -> compact fp32 [t][2048]
        #pragma unroll
        for (int i = 0; i < 4; i++)
            #pragma unroll
            for (int r = 0; r < 4; r++) {
                int grow = row0 + wr + i * 16 + l4 * 4 + r;
                #pragma unroll
                for (int j = 0; j < 4; j++)
                    qkvQK[(long)grow * 2048 + col0 + wc + j * 16 + l16] = acc[i][j][r];
            }
    } else {             // V columns -> split + transposed Vt[bh][d][s], r-packed b64 stores
        #pragma unroll
        for (int i = 0; i < 4; i++) {
            int s0 = row0 + wr + i * 16 + l4 * 4;
            int b = s0 >> 11, sl = s0 & 2047;
            #pragma unroll
            for (int j = 0; j < 4; j++) {
                int d = col0 - 2048 + wc + j * 16 + l16;
                int h = d >> 6, dl = d & 63;
                long base = ((long)(b * NHEAD + h) * 64 + dl) * SEQ + sl;
                bf16x4 vh, vl;
                #pragma unroll
                for (int r = 0; r < 4; r++) { HL sp = split2(acc[i][j][r]); vh[r] = sp.h; vl[r] = sp.l; }
                *(bf16x4*)&VtH[base] = vh;
                *(bf16x4*)&VtL[base] = vl;
            }
        }
    }
}

// ---------------- prep: qkvQK fp32 -> Qh/Ql/Kh/Kl [bh][s][64] ----------------
__global__ __launch_bounds__(256)
void prep_qk_kernel(const float* __restrict__ qkvQK, bf16* __restrict__ Qh, bf16* __restrict__ Ql,
                    bf16* __restrict__ Kh, bf16* __restrict__ Kl) {
    int wave = threadIdx.x >> 6, lane = threadIdx.x & 63;
    int gid = blockIdx.x * 4 + wave;          // [0, 8192)
    int t = gid >> 1, type = gid & 1;
    int b = t >> 11, s = t & 2047;
    const float* src = qkvQK + (long)t * 2048 + type * 1024 + lane * 16;
    bf16* oh = (type ? Kh : Qh);
    bf16* ol = (type ? Kl : Ql);
    int h = lane >> 2;
    long obase = ((long)(b * NHEAD + h) * SEQ + s) * 64 + (lane & 3) * 16;
    #pragma unroll
    for (int c4 = 0; c4 < 4; c4++) {
        f32x4 v = *(const f32x4*)&src[c4 * 4];
        bf16x4 vh, vl;
        #pragma unroll
        for (int j = 0; j < 4; j++) { HL sp = split2(v[j]); vh[j] = sp.h; vl[j] = sp.l; }
        *(bf16x4*)&oh[obase + c4 * 4] = vh;
        *(bf16x4*)&ol[obase + c4 * 4] = vl;
    }
}

// ---------------- flash attention: pre-split Q/K/Vt, split ao epilogue ----------------
__global__ __launch_bounds__(256)
void flash_attn(const bf16* __restrict__ Qh_g, const bf16* __restrict__ Ql_g,
                const bf16* __restrict__ Kh_g, const bf16* __restrict__ Kl_g,
                const bf16* __restrict__ VtH_g, const bf16* __restrict__ VtL_g,
                bf16* __restrict__ aoh, bf16* __restrict__ aol) {
    __shared__ alignas(16) bf16 Qh[64][72], Ql[64][72], Kh[64][72], Kl[64][72];
    __shared__ alignas(16) bf16 Vth[64][72], Vtl[64][72];
    __shared__ alignas(16) bf16 Ph[4][16][72], Pl[4][16][72];
    int tid = threadIdx.x;
    int wave = tid >> 6, lane = tid & 63;
    int l16 = lane & 15, l4 = lane >> 4;
    int bh = blockIdx.y;
    int b = bh >> 4, h = bh & 15;
    int q0 = blockIdx.x * 64;

    const bf16* qh = Qh_g + ((long)bh * SEQ + q0) * 64;
    const bf16* ql = Ql_g + ((long)bh * SEQ + q0) * 64;
    #pragma unroll
    for (int p = 0; p < 2; p++) {
        int idx = p * 2048 + tid * 8; int r = idx >> 6, c = idx & 63;
        *(bf16x8*)&Qh[r][c] = *(const bf16x8*)&qh[r * 64 + c];
        *(bf16x8*)&Ql[r][c] = *(const bf16x8*)&ql[r * 64 + c];
    }
    float m_r[4], l_r[4];
    f32x4 accO[4] = {};
    #pragma unroll
    for (int r = 0; r < 4; r++) { m_r[r] = -1e30f; l_r[r] = 0.f; }

    for (int c0 = 0; c0 < SEQ; c0 += 64) {
        __syncthreads();
        const bf16* kh = Kh_g + ((long)bh * SEQ + c0) * 64;
        const bf16* kl = Kl_g + ((long)bh * SEQ + c0) * 64;
        const bf16* vh = VtH_g + (long)bh * 64 * SEQ + c0;
        const bf16* vl = VtL_g + (long)bh * 64 * SEQ + c0;
        #pragma unroll
        for (int p = 0; p < 2; p++) {
            int idx = p * 2048 + tid * 8; int r = idx >> 6, c = idx & 63;
            *(bf16x8*)&Kh[r][c]  = *(const bf16x8*)&kh[r * 64 + c];
            *(bf16x8*)&Kl[r][c]  = *(const bf16x8*)&kl[r * 64 + c];
            *(bf16x8*)&Vth[r][c] = *(const bf16x8*)&vh[(long)r * SEQ + c];
            *(bf16x8*)&Vtl[r][c] = *(const bf16x8*)&vl[(long)r * SEQ + c];
        }
        __syncthreads();
        f32x4 s[4] = {};
        #pragma unroll
        for (int ks = 0; ks < 2; ks++) {
            bf16x8 aqh = *(const bf16x8*)&Qh[wave * 16 + l16][ks * 32 + l4 * 8];
            bf16x8 aql = *(const bf16x8*)&Ql[wave * 16 + l16][ks * 32 + l4 * 8];
            #pragma unroll
            for (int j = 0; j < 4; j++) {
                bf16x8 bkh = *(const bf16x8*)&Kh[j * 16 + l16][ks * 32 + l4 * 8];
                bf16x8 bkl = *(const bf16x8*)&Kl[j * 16 + l16][ks * 32 + l4 * 8];
                s[j] = __builtin_amdgcn_mfma_f32_16x16x32_bf16(aqh, bkh, s[j], 0, 0, 0);
                s[j] = __builtin_amdgcn_mfma_f32_16x16x32_bf16(aqh, bkl, s[j], 0, 0, 0);
                s[j] = __builtin_amdgcn_mfma_f32_16x16x32_bf16(aql, bkh, s[j], 0, 0, 0);
            }
        }
        #pragma unroll
        for (int j = 0; j < 4; j++)
            #pragma unroll
            for (int r = 0; r < 4; r++) s[j][r] *= 0.125f;
        #pragma unroll
        for (int r = 0; r < 4; r++) {
            float mx = fmaxf(fmaxf(s[0][r], s[1][r]), fmaxf(s[2][r], s[3][r]));
            #pragma unroll
            for (int m = 1; m < 16; m <<= 1) mx = fmaxf(mx, __shfl_xor(mx, m));
            float mnew = fmaxf(m_r[r], mx);
            float alpha = expf(m_r[r] - mnew);
            float psum = 0.f;
            #pragma unroll
            for (int j = 0; j < 4; j++) {
                float pv = expf(s[j][r] - mnew);
                s[j][r] = pv; psum += pv;
            }
            #pragma unroll
            for (int m = 1; m < 16; m <<= 1) psum += __shfl_xor(psum, m);
            l_r[r] = l_r[r] * alpha + psum;
            m_r[r] = mnew;
            #pragma unroll
            for (int j = 0; j < 4; j++) accO[j][r] *= alpha;
        }
        #pragma unroll
        for (int j = 0; j < 4; j++)
            #pragma unroll
            for (int r = 0; r < 4; r++) {
                HL sp = split2(s[j][r]);
                Ph[wave][l4 * 4 + r][j * 16 + l16] = sp.h;
                Pl[wave][l4 * 4 + r][j * 16 + l16] = sp.l;
            }
        #pragma unroll
        for (int ks = 0; ks < 2; ks++) {
            bf16x8 aph = *(const bf16x8*)&Ph[wave][l16][ks * 32 + l4 * 8];
            bf16x8 apl = *(const bf16x8*)&Pl[wave][l16][ks * 32 + l4 * 8];
            #pragma unroll
            for (int j = 0; j < 4; j++) {
                bf16x8 bvh = *(const bf16x8*)&Vth[j * 16 + l16][ks * 32 + l4 * 8];
                bf16x8 bvl = *(const bf16x8*)&Vtl[j * 16 + l16][ks * 32 + l4 * 8];
                accO[j] = __builtin_amdgcn_mfma_f32_16x16x32_bf16(aph, bvh, accO[j], 0, 0, 0);
                accO[j] = __builtin_amdgcn_mfma_f32_16x16x32_bf16(aph, bvl, accO[j], 0, 0, 0);
                accO[j] = __builtin_amdgcn_mfma_f32_16x16x32_bf16(apl, bvh, accO[j], 0, 0, 0);
            }
        }
    }
    #pragma unroll
    for (int j = 0; j < 4; j++)
        #pragma unroll
        for (int r = 0; r < 4; r++) {
            int grow = q0 + wave * 16 + l4 * 4 + r;
            long o = ((long)(b * SEQ + grow)) * DIM + h * 64 + j * 16 + l16;
            HL sp = split2(accO[j][r] / l_r[r]);
            aoh[o] = sp.h; aol[o] = sp.l;
        }
}

// ---------------- proj GEMM (pre-split inputs): C = A@Bt^T + bias + residual -> fp32 ----------------
__global__ __launch_bounds__(256)
void gemm_proj(const bf16* __restrict__ Ah_g, const bf16* __restrict__ Al_g,
               const bf16* __restrict__ Bh_g, const bf16* __restrict__ Bl_g,
               const float* __restrict__ bias, const float* __restrict__ res,
               float* __restrict__ C, int N, int K) {
    __shared__ alignas(16) bf16 Ah[128][72], Al[128][72], Bh[128][72], Bl[128][72];
    int tid = threadIdx.x;
    int wave = tid >> 6, lane = tid & 63;
    int l16 = lane & 15, l4 = lane >> 4;
    int wr = (wave >> 1) * 64, wc = (wave & 1) * 64;
    int row0 = blockIdx.y * 128, col0 = blockIdx.x * 128;
    f32x4 acc[4][4] = {};
    for (int k0 = 0; k0 < K; k0 += 64) {
        #pragma unroll
        for (int p = 0; p < 4; p++) {
            int idx = p * 2048 + tid * 8; int r = idx >> 6, c = idx & 63;
            *(bf16x8*)&Ah[r][c] = *(const bf16x8*)&Ah_g[(long)(row0 + r) * K + k0 + c];
            *(bf16x8*)&Al[r][c] = *(const bf16x8*)&Al_g[(long)(row0 + r) * K + k0 + c];
            *(bf16x8*)&Bh[r][c] = *(const bf16x8*)&Bh_g[(long)(col0 + r) * K + k0 + c];
            *(bf16x8*)&Bl[r][c] = *(const bf16x8*)&Bl_g[(long)(col0 + r) * K + k0 + c];
        }
        __syncthreads();
        #pragma unroll
        for (int ks = 0; ks < 2; ks++) {
            bf16x8 ah[4], al[4], bh[4], bl[4];
            #pragma unroll
            for (int i = 0; i < 4; i++) {
                ah[i] = *(const bf16x8*)&Ah[wr + i*16 + l16][ks*32 + l4*8];
                al[i] = *(const bf16x8*)&Al[wr + i*16 + l16][ks*32 + l4*8];
            }
            #pragma unroll
            for (int j = 0; j < 4; j++) {
                bh[j] = *(const bf16x8*)&Bh[wc + j*16 + l16][ks*32 + l4*8];
                bl[j] = *(const bf16x8*)&Bl[wc + j*16 + l16][ks*32 + l4*8];
            }
            #pragma unroll
            for (int i = 0; i < 4; i++)
                #pragma unroll
                for (int j = 0; j < 4; j++) {
                    acc[i][j] = __builtin_amdgcn_mfma_f32_16x16x32_bf16(ah[i], bh[j], acc[i][j], 0, 0, 0);
                    acc[i][j] = __builtin_amdgcn_mfma_f32_16x16x32_bf16(ah[i], bl[j], acc[i][j], 0, 0, 0);
                    acc[i][j] = __builtin_amdgcn_mfma_f32_16x16x32_bf16(al[i], bh[j], acc[i][j], 0, 0, 0);
                }
        }
        __syncthreads();
    }
    #pragma unroll
    for (int i = 0; i < 4; i++)
        #pragma unroll
        for (int r = 0; r < 4; r++) {
            int grow = row0 + wr + i * 16 + l4 * 4 + r;
            #pragma unroll
            for (int j = 0; j < 4; j++) {
                int gcol = col0 + wc + j * 16 + l16;
                long o = (long)grow * N + gcol;
                C[o] = acc[i][j][r] + bias[gcol] + res[o];
            }
        }
}

// ---------------- plain bf16 GEMM, expert-batched via blockIdx.z ----------------
// OUT_MODE 0: bf16 store; 2: fp32 += v; 3: atomicAdd(Cf[rowmap[row]*N+col], roww[row]*v)
template<bool BIAS, bool GELU, bool GATHER, int OUT_MODE>
__global__ __launch_bounds__(256)
void gemm_bt(const bf16* __restrict__ A, const bf16* __restrict__ Bt,
             const float* __restrict__ bias,
             bf16* __restrict__ Cbf, float* __restrict__ Cf,
             const int* __restrict__ rowmap, const float* __restrict__ roww,
             int M, int N, int K,
             long eA, long eB, long ebias, long eMap, long eC) {
    int ez = blockIdx.z;
    A += (long)ez * eA; Bt += (long)ez * eB;
    if (BIAS) bias += (long)ez * ebias;
    if (GATHER || OUT_MODE == 3) rowmap += (long)ez * eMap;
    if (OUT_MODE == 3) roww += (long)ez * eMap;
    if (OUT_MODE == 0) Cbf += (long)ez * eC;

    __shared__ alignas(16) bf16 As[128][72];
    __shared__ alignas(16) bf16 Bs[128][72];
    int tid = threadIdx.x;
    int wave = tid >> 6, lane = tid & 63;
    int l16 = lane & 15, l4 = lane >> 4;
    int wr = (wave >> 1) * 64, wc = (wave & 1) * 64;
    int row0 = blockIdx.y * 128, col0 = blockIdx.x * 128;

    int sr[4], sc[4]; long arow[4];
    #pragma unroll
    for (int p = 0; p < 4; p++) {
        int idx = p * 2048 + tid * 8;
        sr[p] = idx >> 6; sc[p] = idx & 63;
        long gr = row0 + sr[p];
        if (GATHER) gr = rowmap[gr];
        arow[p] = gr;
    }
    f32x4 acc[4][4] = {};
    for (int k0 = 0; k0 < K; k0 += 64) {
        #pragma unroll
        for (int p = 0; p < 4; p++) {
            *(bf16x8*)&As[sr[p]][sc[p]] = *(const bf16x8*)&A[arow[p] * K + k0 + sc[p]];
            *(bf16x8*)&Bs[sr[p]][sc[p]] = *(const bf16x8*)&Bt[(long)(col0 + sr[p]) * K + k0 + sc[p]];
        }
        __syncthreads();
        #pragma unroll
        for (int ks = 0; ks < 2; ks++) {
            bf16x8 af[4], bfr[4];
            #pragma unroll
            for (int i = 0; i < 4; i++) af[i]  = *(const bf16x8*)&As[wr + i*16 + l16][ks*32 + l4*8];
            #pragma unroll
            for (int j = 0; j < 4; j++) bfr[j] = *(const bf16x8*)&Bs[wc + j*16 + l16][ks*32 + l4*8];
            #pragma unroll
            for (int i = 0; i < 4; i++)
                #pragma unroll
                for (int j = 0; j < 4; j++)
                    acc[i][j] = __builtin_amdgcn_mfma_f32_16x16x32_bf16(af[i], bfr[j], acc[i][j], 0, 0, 0);
        }
        __syncthreads();
    }
    #pragma unroll
    for (int i = 0; i < 4; i++)
        #pragma unroll
        for (int r = 0; r < 4; r++) {
            int grow = row0 + wr + i * 16 + l4 * 4 + r;
            int st = 0; float sw = 0.f;
            if (OUT_MODE == 3) { st = rowmap[grow]; sw = roww[grow]; }
            #pragma unroll
            for (int j = 0; j < 4; j++) {
                int gcol = col0 + wc + j * 16 + l16;
                float v = acc[i][j][r];
                if (BIAS) v += bias[gcol];
                if (GELU) v = gelu_exact(v);
                if (OUT_MODE == 0) {
                    Cbf[(long)grow * N + gcol] = (bf16)v;
                } else if (OUT_MODE == 2) {
                    long o = (long)grow * N + gcol;
                    Cf[o] += v;
                } else {
                    atomicAdd(&Cf[(long)st * N + gcol], sw * v);
                }
            }
        }
}

// ---------------- routing (pure fp32, LN inline): one wave per token ----------------
__global__ __launch_bounds__(256)
void routing_kernel(const float* __restrict__ xres, const float* __restrict__ g,
                    const float* __restrict__ b, const float* __restrict__ w_route,
                    const float* __restrict__ b_route, const float* __restrict__ w_noise,
                    const float* __restrict__ b_noise, const float* __restrict__ noise,
                    int* __restrict__ topi, float* __restrict__ topp) {
    int wave = threadIdx.x >> 6, lane = threadIdx.x & 63;
    long t = (long)blockIdx.x * 4 + wave;
    const float* xr = xres + t * DIM;
    float v[16];
    #pragma unroll
    for (int i = 0; i < 16; i++) v[i] = xr[i * 64 + lane];
    float s = 0.f, s2 = 0.f;
    #pragma unroll
    for (int i = 0; i < 16; i++) { s += v[i]; s2 += v[i] * v[i]; }
    #pragma unroll
    for (int m = 1; m < 64; m <<= 1) { s += __shfl_xor(s, m); s2 += __shfl_xor(s2, m); }
    float mu  = s * (1.f / DIM);
    float var = s2 * (1.f / DIM) - mu * mu;
    float rs  = 1.f / sqrtf(var + 1e-5f);
    float accr[4] = {0.f,0.f,0.f,0.f}, accn[4] = {0.f,0.f,0.f,0.f};
    #pragma unroll
    for (int i = 0; i < 16; i++) {
        int d = i * 64 + lane;
        float n = (v[i] - mu) * rs * g[d] + b[d];
        #pragma unroll
        for (int e = 0; e < 4; e++) {
            accr[e] += n * w_route[d * 4 + e];
            accn[e] += n * w_noise[d * 4 + e];
        }
    }
    #pragma unroll
    for (int e = 0; e < 4; e++)
        #pragma unroll
        for (int m = 1; m < 64; m <<= 1) {
            accr[e] += __shfl_xor(accr[e], m);
            accn[e] += __shfl_xor(accn[e], m);
        }
    if (lane == 0) {
        float nz[4];
        #pragma unroll
        for (int e = 0; e < 4; e++) {
            float logit = accr[e] + b_route[e];
            float si = accn[e] + b_noise[e];
            float sp = si > 0.f ? si + log1pf(expf(-si)) : log1pf(expf(si));
            nz[e] = logit + noise[t * 4 + e] * sp;
        }
        int i1 = 0;
        #pragma unroll
        for (int e = 1; e < 4; e++) if (nz[e] > nz[i1]) i1 = e;
        int i2 = -1; float v2 = -1e30f;
        #pragma unroll
        for (int e = 0; e < 4; e++) if (e != i1 && nz[e] > v2) { v2 = nz[e]; i2 = e; }
        float ex = expf(v2 - nz[i1]);
        topi[t * 2]     = i1; topi[t * 2 + 1] = i2;
        topp[t * 2]     = 1.f / (1.f + ex);
        topp[t * 2 + 1] = ex / (1.f + ex);
    }
}

// ---------------- dispatch: per-expert ordered token lists (wave e = expert e) ----------------
__global__ __launch_bounds__(256)
void dispatch_kernel(const int* __restrict__ topi, const float* __restrict__ topp,
                     int* __restrict__ sel, float* __restrict__ wgt) {
    int e = threadIdx.x >> 6, lane = threadIdx.x & 63;
    int cnt = 0;
    for (int c = 0; c < T_TOK; c += 64) {
        int t = c + lane;
        int i0 = topi[t * 2], i1 = topi[t * 2 + 1];
        bool m = (i0 == e) || (i1 == e);
        unsigned long long bal = __ballot(m);
        int pos = cnt + __popcll(bal & ((1ull << lane) - 1ull));
        if (m && pos < CAP) {
            sel[e * CAP + pos] = t;
            wgt[e * CAP + pos] = (i0 == e) ? topp[t * 2] : topp[t * 2 + 1];
        }
        cnt += (int)__popcll(bal);
    }
    if (cnt > CAP) cnt = CAP;
    for (int pos = cnt + lane; pos < CAP; pos += 64) {
        sel[e * CAP + pos] = 0;
        wgt[e * CAP + pos] = 0.f;
    }
}

extern "C" void kernel_launch(void* const* d_in, const int* in_sizes, int n_in,
                              void* d_out, int out_size, void* d_ws, size_t ws_size,
                              hipStream_t stream) {
    (void)in_sizes; (void)n_in; (void)out_size; (void)ws_size;
    const float* x       = (const float*)d_in[0];
    const float* noise   = (const float*)d_in[1];
    const float* ln1_g   = (const float*)d_in[2];
    const float* ln1_b   = (const float*)d_in[3];
    const float* ln2_g   = (const float*)d_in[4];
    const float* ln2_b   = (const float*)d_in[5];
    const float* w_qkv   = (const float*)d_in[6];
    const float* w_proj  = (const float*)d_in[7];
    const float* b_proj  = (const float*)d_in[8];
    const float* w_route = (const float*)d_in[9];
    const float* b_route = (const float*)d_in[10];
    const float* w_noise = (const float*)d_in[11];
    const float* b_noise = (const float*)d_in[12];
    const float* we1     = (const float*)d_in[13];
    const float* be1     = (const float*)d_in[14];
    const float* we2     = (const float*)d_in[15];
    const float* be2     = (const float*)d_in[16];
    const float* w_mlp1  = (const float*)d_in[17];
    const float* b_mlp1  = (const float*)d_in[18];
    const float* w_mlp2  = (const float*)d_in[19];
    const float* b_mlp2  = (const float*)d_in[20];
    float* d_outf = (float*)d_out;

    // ---- workspace regions (total 88.1 MB) ----
    char* p = (char*)d_ws;
    char* R1 = p; p += 33554432;   // qkvQK fp32 [4096][2048] -> aoh/aol -> h_mlp
    char* R2 = p; p += 33554432;   // x1h/x1l/wqkvh/wqkvl -> Qh/Ql/Kh/Kl -> wmlpT/weT/h_e
    char* R3 = p; p += 16777216;   // VtH/VtL -> x2b + topi/topp/sel/wgt
    char* R4 = p; p += 4194304;    // wprojh/wprojl (alive until proj)

    float* qkvQK  = (float*)R1;
    bf16*  aoh    = (bf16*)R1;
    bf16*  aol    = (bf16*)(R1 + 8388608);
    bf16*  h_mlp  = (bf16*)R1;

    bf16* x1h    = (bf16*)R2;
    bf16* x1l    = (bf16*)(R2 + 8388608);
    bf16* wqkvh  = (bf16*)(R2 + 16777216);
    bf16* wqkvl  = (bf16*)(R2 + 23068672);
    bf16* Qh     = (bf16*)R2;
    bf16* Ql     = (bf16*)(R2 + 8388608);
    bf16* Kh     = (bf16*)(R2 + 16777216);
    bf16* Kl     = (bf16*)(R2 + 25165824);
    bf16* w_mlp1T = (bf16*)R2;
    bf16* w_mlp2T = (bf16*)(R2 + 8388608);
    bf16* we1T    = (bf16*)(R2 + 16777216);
    bf16* we2T    = (bf16*)(R2 + 18874368);
    bf16* h_e     = (bf16*)(R2 + 20971520);

    bf16*  VtH  = (bf16*)R3;
    bf16*  VtL  = (bf16*)(R3 + 8388608);
    bf16*  x2b  = (bf16*)R3;
    int*   topi = (int*)(R3 + 8388608);
    float* topp = (float*)(R3 + 8421376);
    int*   sel  = (int*)(R3 + 8454144);
    float* wgt  = (float*)(R3 + 8486912);

    bf16* wprojh = (bf16*)R4;
    bf16* wprojl = (bf16*)(R4 + 2097152);

    // ---- phase 1: LN1-split, weight splits ----
    ln_split_kernel<<<T_TOK/4, 256, 0, stream>>>(x, ln1_g, ln1_b, x1h, x1l);
    split_pair_kernel<<<(3*DIM*DIM)/1024, 256, 0, stream>>>(w_qkv, wqkvh, wqkvl);
    split_pair_kernel<<<(DIM*DIM)/1024,   256, 0, stream>>>(w_proj, wprojh, wprojl);

    // ---- phase 2: qkv GEMM (epilogue: Q/K->qkvQK fp32, V->split Vt) ----
    gemm_qkv<<<dim3(3*DIM/128, T_TOK/128), 256, 0, stream>>>(
        x1h, x1l, wqkvh, wqkvl, qkvQK, VtH, VtL);

    // ---- phase 3: Q/K split-compaction, then flash attention ----
    prep_qk_kernel<<<2048, 256, 0, stream>>>(qkvQK, Qh, Ql, Kh, Kl);
    flash_attn<<<dim3(SEQ/64, 2*NHEAD), 256, 0, stream>>>(Qh, Ql, Kh, Kl, VtH, VtL, aoh, aol);

    // ---- phase 4: proj + bias + residual -> d_out (fp32 stream) ----
    gemm_proj<<<dim3(DIM/128, T_TOK/128), 256, 0, stream>>>(
        aoh, aol, wprojh, wprojl, b_proj, x, d_outf, DIM, DIM);

    // ---- phase 5: LN2 (bf16) + routing + dispatch ----
    ln_kernel<<<T_TOK/4, 256, 0, stream>>>(d_outf, ln2_g, ln2_b, x2b);
    routing_kernel<<<T_TOK/4, 256, 0, stream>>>(d_outf, ln2_g, ln2_b, w_route, b_route,
                                                w_noise, b_noise, noise, topi, topp);
    dispatch_kernel<<<1, 256, 0, stream>>>(topi, topp, sel, wgt);

    // ---- phase 6: weight transposes (into R2; QK splits dead) ----
    transpose_conv_kernel<<<dim3(MLPH/32, DIM/32, 1),    256, 0, stream>>>(w_mlp1, w_mlp1T, DIM, MLPH);
    transpose_conv_kernel<<<dim3(DIM/32, MLPH/32, 1),    256, 0, stream>>>(w_mlp2, w_mlp2T, MLPH, DIM);
    transpose_conv_kernel<<<dim3(MOEH/32, DIM/32, NEXP), 256, 0, stream>>>(we1, we1T, DIM, MOEH);
    transpose_conv_kernel<<<dim3(DIM/32, MOEH/32, NEXP), 256, 0, stream>>>(we2, we2T, MOEH, DIM);

    // ---- phase 7: dense MLP (mlp2 accumulates into d_out) ----
    gemm_bt<true,true,false,0><<<dim3(MLPH/128, T_TOK/128), 256, 0, stream>>>(
        x2b, w_mlp1T, b_mlp1, h_mlp, nullptr, nullptr, nullptr, T_TOK, MLPH, DIM,
        0, 0, 0, 0, 0);
    gemm_bt<true,false,false,2><<<dim3(DIM/128, T_TOK/128), 256, 0, stream>>>(
        h_mlp, w_mlp2T, b_mlp2, nullptr, d_outf, nullptr, nullptr, T_TOK, DIM, MLPH,
        0, 0, 0, 0, 0);

    // ---- phase 8: MoE experts, batched over blockIdx.z ----
    gemm_bt<true,true,true,0><<<dim3(MOEH/128, CAP/128, NEXP), 256, 0, stream>>>(
        x2b, we1T, be1, h_e, nullptr, sel, nullptr, CAP, MOEH, DIM,
        0, (long)MOEH*DIM, MOEH, CAP, (long)CAP*MOEH);
    gemm_bt<true,false,false,3><<<dim3(DIM/128, CAP/128, NEXP), 256, 0, stream>>>(
        h_e, we2T, be2, nullptr, d_outf, sel, wgt, CAP, DIM, MOEH,
        (long)CAP*MOEH, (long)DIM*MOEH, DIM, CAP, 0);
}

// Round 6
// 806.674 us; speedup vs baseline: 1.3048x; 1.2212x over previous
//
#include <hip/hip_runtime.h>
#include <hip/hip_bf16.h>
#include <math.h>

typedef __bf16 bf16;
typedef __bf16 bf16x4 __attribute__((ext_vector_type(4)));
typedef __bf16 bf16x8 __attribute__((ext_vector_type(8)));
typedef float  f32x4  __attribute__((ext_vector_type(4)));

#define T_TOK 4096
#define DIM   1024
#define NHEAD 16
#define SEQ   2048
#define NEXP  4
#define CAP   2048
#define MLPH  4096
#define MOEH  256

__device__ __forceinline__ float gelu_exact(float v) {
    return 0.5f * v * (1.f + erff(v * 0.70710678118654752f));
}

struct HL { bf16 h, l; };
__device__ __forceinline__ HL split2(float v) {
    HL r; r.h = (bf16)v; r.l = (bf16)(v - (float)r.h); return r;
}

// async global->LDS, 16B per lane; LDS dest = wave-uniform base + lane*16
__device__ __forceinline__ void gload16(const bf16* gptr, bf16* lptr) {
    __builtin_amdgcn_global_load_lds(
        (const __attribute__((address_space(1))) unsigned int*)gptr,
        (__attribute__((address_space(3))) unsigned int*)lptr,
        16, 0, 0);
}

// ---------------- LN1 -> hi/lo bf16 planes: one wave per token ----------------
__global__ __launch_bounds__(256)
void ln_split_kernel(const float* __restrict__ x, const float* __restrict__ g,
                     const float* __restrict__ b, bf16* __restrict__ oh, bf16* __restrict__ ol) {
    int wave = threadIdx.x >> 6, lane = threadIdx.x & 63;
    long t = (long)blockIdx.x * 4 + wave;
    const float* xr = x + t * DIM;
    float v[16];
    #pragma unroll
    for (int i = 0; i < 16; i++) v[i] = xr[i * 64 + lane];
    float s = 0.f, s2 = 0.f;
    #pragma unroll
    for (int i = 0; i < 16; i++) { s += v[i]; s2 += v[i] * v[i]; }
    #pragma unroll
    for (int m = 1; m < 64; m <<= 1) { s += __shfl_xor(s, m); s2 += __shfl_xor(s2, m); }
    float mu  = s * (1.f / DIM);
    float var = s2 * (1.f / DIM) - mu * mu;
    float rs  = 1.f / sqrtf(var + 1e-5f);
    #pragma unroll
    for (int i = 0; i < 16; i++) {
        int d = i * 64 + lane;
        HL sp = split2((v[i] - mu) * rs * g[d] + b[d]);
        oh[t * DIM + d] = sp.h; ol[t * DIM + d] = sp.l;
    }
}

// ---------------- LN (fp32 in -> bf16 out): one wave per token ----------------
__global__ __launch_bounds__(256)
void ln_kernel(const float* __restrict__ x, const float* __restrict__ g,
               const float* __restrict__ b, bf16* __restrict__ out) {
    int wave = threadIdx.x >> 6, lane = threadIdx.x & 63;
    long t = (long)blockIdx.x * 4 + wave;
    const float* xr = x + t * DIM;
    float v[16];
    #pragma unroll
    for (int i = 0; i < 16; i++) v[i] = xr[i * 64 + lane];
    float s = 0.f, s2 = 0.f;
    #pragma unroll
    for (int i = 0; i < 16; i++) { s += v[i]; s2 += v[i] * v[i]; }
    #pragma unroll
    for (int m = 1; m < 64; m <<= 1) { s += __shfl_xor(s, m); s2 += __shfl_xor(s2, m); }
    float mu  = s * (1.f / DIM);
    float var = s2 * (1.f / DIM) - mu * mu;
    float rs  = 1.f / sqrtf(var + 1e-5f);
    #pragma unroll
    for (int i = 0; i < 16; i++) {
        int d = i * 64 + lane;
        out[t * DIM + d] = (bf16)((v[i] - mu) * rs * g[d] + b[d]);
    }
}

// ---------------- elementwise fp32 -> hi/lo planes ----------------
__global__ __launch_bounds__(256)
void split_pair_kernel(const float* __restrict__ in, bf16* __restrict__ h, bf16* __restrict__ l) {
    long i0 = ((long)blockIdx.x * 256 + threadIdx.x) * 4;
    f32x4 v = *(const f32x4*)&in[i0];
    bf16x4 vh, vl;
    #pragma unroll
    for (int j = 0; j < 4; j++) { HL sp = split2(v[j]); vh[j] = sp.h; vl[j] = sp.l; }
    *(bf16x4*)&h[i0] = vh; *(bf16x4*)&l[i0] = vl;
}

// ---------------- transpose fp32 -> bf16 (32x32 tiles, batched in z) ----------------
__global__ __launch_bounds__(256)
void transpose_conv_kernel(const float* __restrict__ in, bf16* __restrict__ out, int R, int C) {
    __shared__ bf16 tile[32][33];
    long bo = (long)blockIdx.z * R * C;
    in += bo; out += bo;
    int c0 = blockIdx.x * 32, r0 = blockIdx.y * 32;
    int tx = threadIdx.x & 31, ty = threadIdx.x >> 5;
    #pragma unroll
    for (int i = 0; i < 32; i += 8)
        tile[ty + i][tx] = (bf16)in[(long)(r0 + ty + i) * C + c0 + tx];
    __syncthreads();
    #pragma unroll
    for (int i = 0; i < 32; i += 8)
        out[(long)(c0 + ty + i) * R + r0 + tx] = tile[tx][ty + i];
}

// ---------------- qkv split GEMM: glds staging; epilogue -> Q/K split planes + split Vt ----------------
__global__ __launch_bounds__(256)
void gemm_qkv(const bf16* __restrict__ Ah_g, const bf16* __restrict__ Al_g,
              const bf16* __restrict__ Bh_g, const bf16* __restrict__ Bl_g,
              bf16* __restrict__ Qh_g, bf16* __restrict__ Ql_g,
              bf16* __restrict__ Kh_g, bf16* __restrict__ Kl_g,
              bf16* __restrict__ VtH, bf16* __restrict__ VtL) {
    const int K = DIM;
    __shared__ alignas(16) bf16 Ah[8192], Al[8192], Bh[8192], Bl[8192];
    int tid = threadIdx.x;
    int wave = tid >> 6, lane = tid & 63;
    int l16 = lane & 15, l4 = lane >> 4;
    int wr = (wave >> 1) * 64, wc = (wave & 1) * 64;
    int row0 = blockIdx.y * 128, col0 = blockIdx.x * 128;
    int colb = (lane & 7) * 8;
    f32x4 acc[4][4] = {};
    for (int k0 = 0; k0 < K; k0 += 64) {
        #pragma unroll
        for (int p = 0; p < 4; p++) {
            int rl = p * 32 + wave * 8 + (lane >> 3);
            int lb = p * 2048 + wave * 512;
            gload16(&Ah_g[(long)(row0 + rl) * K + k0 + colb], &Ah[lb]);
            gload16(&Al_g[(long)(row0 + rl) * K + k0 + colb], &Al[lb]);
            gload16(&Bh_g[(long)(col0 + rl) * K + k0 + colb], &Bh[lb]);
            gload16(&Bl_g[(long)(col0 + rl) * K + k0 + colb], &Bl[lb]);
        }
        __syncthreads();
        #pragma unroll
        for (int ks = 0; ks < 2; ks++) {
            bf16x8 ah[4], al[4], bh[4], bl[4];
            #pragma unroll
            for (int i = 0; i < 4; i++) {
                ah[i] = *(const bf16x8*)&Ah[(wr + i*16 + l16)*64 + ks*32 + l4*8];
                al[i] = *(const bf16x8*)&Al[(wr + i*16 + l16)*64 + ks*32 + l4*8];
            }
            #pragma unroll
            for (int j = 0; j < 4; j++) {
                bh[j] = *(const bf16x8*)&Bh[(wc + j*16 + l16)*64 + ks*32 + l4*8];
                bl[j] = *(const bf16x8*)&Bl[(wc + j*16 + l16)*64 + ks*32 + l4*8];
            }
            #pragma unroll
            for (int i = 0; i < 4; i++)
                #pragma unroll
                for (int j = 0; j < 4; j++) {
                    acc[i][j] = __builtin_amdgcn_mfma_f32_16x16x32_bf16(ah[i], bh[j], acc[i][j], 0, 0, 0);
                    acc[i][j] = __builtin_amdgcn_mfma_f32_16x16x32_bf16(ah[i], bl[j], acc[i][j], 0, 0, 0);
                    acc[i][j] = __builtin_amdgcn_mfma_f32_16x16x32_bf16(al[i], bh[j], acc[i][j], 0, 0, 0);
                }
        }
        __syncthreads();
    }
    if (col0 < 2048) {   // Q/K columns -> split planes [bh][s][64]
        bf16* oh = (col0 < 1024) ? Qh_g : Kh_g;
        bf16* ol = (col0 < 1024) ? Ql_g : Kl_g;
        #pragma unroll
        for (int i = 0; i < 4; i++)
            #pragma unroll
            for (int r = 0; r < 4; r++) {
                int t = row0 + wr + i * 16 + l4 * 4 + r;
                int bq = t >> 11, s = t & 2047;
                #pragma unroll
                for (int j = 0; j < 4; j++) {
                    int col = (col0 + wc + j * 16 + l16) & 1023;
                    int hh = col >> 6, dl = col & 63;
                    long o = ((long)(bq * NHEAD + hh) * SEQ + s) * 64 + dl;
                    HL sp = split2(acc[i][j][r]);
                    oh[o] = sp.h; ol[o] = sp.l;
                }
            }
    } else {             // V columns -> split + transposed Vt[bh][d][s], r-packed b64 stores
        #pragma unroll
        for (int i = 0; i < 4; i++) {
            int s0 = row0 + wr + i * 16 + l4 * 4;
            int b = s0 >> 11, sl = s0 & 2047;
            #pragma unroll
            for (int j = 0; j < 4; j++) {
                int d = col0 - 2048 + wc + j * 16 + l16;
                int h = d >> 6, dl = d & 63;
                long base = ((long)(b * NHEAD + h) * 64 + dl) * SEQ + sl;
                bf16x4 vh, vl;
                #pragma unroll
                for (int r = 0; r < 4; r++) { HL sp = split2(acc[i][j][r]); vh[r] = sp.h; vl[r] = sp.l; }
                *(bf16x4*)&VtH[base] = vh;
                *(bf16x4*)&VtL[base] = vl;
            }
        }
    }
}

// ---------------- flash attention: S^T orientation, glds staging, per-lane q-column softmax ----------------
__global__ __launch_bounds__(256)
void flash_attn(const bf16* __restrict__ Qh_g, const bf16* __restrict__ Ql_g,
                const bf16* __restrict__ Kh_g, const bf16* __restrict__ Kl_g,
                const bf16* __restrict__ VtH_g, const bf16* __restrict__ VtL_g,
                bf16* __restrict__ aoh, bf16* __restrict__ aol) {
    __shared__ alignas(16) bf16 Qh[4096], Ql[4096], Kh[4096], Kl[4096], Vth[4096], Vtl[4096];
    __shared__ alignas(16) bf16 Pth[4][16][72], Ptl[4][16][72];
    int tid = threadIdx.x;
    int wave = tid >> 6, lane = tid & 63;
    int l16 = lane & 15, l4 = lane >> 4;
    int bh = blockIdx.y;
    int b = bh >> 4, h = bh & 15;
    int q0 = blockIdx.x * 64;

    // stage Q tile (contiguous 64x64 in [bh][s][64])
    {
        const bf16* qh = Qh_g + ((long)bh * SEQ + q0) * 64;
        const bf16* ql = Ql_g + ((long)bh * SEQ + q0) * 64;
        #pragma unroll
        for (int p = 0; p < 2; p++) {
            int off = wave * 1024 + p * 512;
            gload16(&qh[off + lane * 8], &Qh[off]);
            gload16(&ql[off + lane * 8], &Ql[off]);
        }
    }
    float m_s = -1e30f, l_s = 0.f;
    f32x4 accO[4] = {};

    for (int c0 = 0; c0 < SEQ; c0 += 64) {
        __syncthreads();   // prev iter's LDS reads done; also drains outstanding glds
        {
            const bf16* kh = Kh_g + ((long)bh * SEQ + c0) * 64;
            const bf16* kl = Kl_g + ((long)bh * SEQ + c0) * 64;
            const bf16* vh = VtH_g + (long)bh * 64 * SEQ + c0;
            const bf16* vl = VtL_g + (long)bh * 64 * SEQ + c0;
            #pragma unroll
            for (int p = 0; p < 2; p++) {
                int off = wave * 1024 + p * 512;
                int e = off + lane * 8;
                gload16(&kh[e], &Kh[off]);
                gload16(&kl[e], &Kl[off]);
                int row = e >> 6, col = e & 63;
                gload16(&vh[(long)row * SEQ + col], &Vth[off]);
                gload16(&vl[(long)row * SEQ + col], &Vtl[off]);
            }
        }
        __syncthreads();
        // S^T[key][q] = K Q^T for keys [0,64), q-cols [wave*16, +16)
        f32x4 st[4] = {};
        #pragma unroll
        for (int ks = 0; ks < 2; ks++) {
            bf16x8 bqh = *(const bf16x8*)&Qh[(wave * 16 + l16) * 64 + ks * 32 + l4 * 8];
            bf16x8 bql = *(const bf16x8*)&Ql[(wave * 16 + l16) * 64 + ks * 32 + l4 * 8];
            #pragma unroll
            for (int i = 0; i < 4; i++) {
                bf16x8 akh = *(const bf16x8*)&Kh[(i * 16 + l16) * 64 + ks * 32 + l4 * 8];
                bf16x8 akl = *(const bf16x8*)&Kl[(i * 16 + l16) * 64 + ks * 32 + l4 * 8];
                st[i] = __builtin_amdgcn_mfma_f32_16x16x32_bf16(akh, bqh, st[i], 0, 0, 0);
                st[i] = __builtin_amdgcn_mfma_f32_16x16x32_bf16(akl, bqh, st[i], 0, 0, 0);
                st[i] = __builtin_amdgcn_mfma_f32_16x16x32_bf16(akh, bql, st[i], 0, 0, 0);
            }
        }
        #pragma unroll
        for (int i = 0; i < 4; i++)
            #pragma unroll
            for (int r = 0; r < 4; r++) st[i][r] *= 0.125f;
        // online softmax over this lane's q-column (16 keys in-reg + 2 shuffles over l4)
        float mx = st[0][0];
        #pragma unroll
        for (int i = 0; i < 4; i++)
            #pragma unroll
            for (int r = 0; r < 4; r++) mx = fmaxf(mx, st[i][r]);
        mx = fmaxf(mx, __shfl_xor(mx, 16));
        mx = fmaxf(mx, __shfl_xor(mx, 32));
        float mnew = fmaxf(m_s, mx);
        float alpha = expf(m_s - mnew);
        float psum = 0.f;
        #pragma unroll
        for (int i = 0; i < 4; i++)
            #pragma unroll
            for (int r = 0; r < 4; r++) {
                float pv = expf(st[i][r] - mnew);
                st[i][r] = pv; psum += pv;
            }
        psum += __shfl_xor(psum, 16);
        psum += __shfl_xor(psum, 32);
        l_s = l_s * alpha + psum;
        m_s = mnew;
        #pragma unroll
        for (int i = 0; i < 4; i++)
            #pragma unroll
            for (int r = 0; r < 4; r++) accO[i][r] *= alpha;
        // P^T -> Pt[wave][q][s] (r-contiguous b64 stores)
        #pragma unroll
        for (int i = 0; i < 4; i++) {
            bf16x4 ph, pl;
            #pragma unroll
            for (int r = 0; r < 4; r++) { HL sp = split2(st[i][r]); ph[r] = sp.h; pl[r] = sp.l; }
            *(bf16x4*)&Pth[wave][l16][i * 16 + l4 * 4] = ph;
            *(bf16x4*)&Ptl[wave][l16][i * 16 + l4 * 4] = pl;
        }
        // O^T += Vt @ P^T (A = Vt, B = P; same-wave LDS dep -> compiler lgkmcnt)
        #pragma unroll
        for (int ks = 0; ks < 2; ks++) {
            bf16x8 bph = *(const bf16x8*)&Pth[wave][l16][ks * 32 + l4 * 8];
            bf16x8 bpl = *(const bf16x8*)&Ptl[wave][l16][ks * 32 + l4 * 8];
            #pragma unroll
            for (int i = 0; i < 4; i++) {
                bf16x8 avh = *(const bf16x8*)&Vth[(i * 16 + l16) * 64 + ks * 32 + l4 * 8];
                bf16x8 avl = *(const bf16x8*)&Vtl[(i * 16 + l16) * 64 + ks * 32 + l4 * 8];
                accO[i] = __builtin_amdgcn_mfma_f32_16x16x32_bf16(avh, bph, accO[i], 0, 0, 0);
                accO[i] = __builtin_amdgcn_mfma_f32_16x16x32_bf16(avh, bpl, accO[i], 0, 0, 0);
                accO[i] = __builtin_amdgcn_mfma_f32_16x16x32_bf16(avl, bph, accO[i], 0, 0, 0);
            }
        }
    }
    // epilogue: lane owns q = q0 + wave*16 + l16; d = i*16 + l4*4 + r -> b64 packed
    float inv = 1.f / l_s;
    int q = q0 + wave * 16 + l16;
    #pragma unroll
    for (int i = 0; i < 4; i++) {
        bf16x4 oh4, ol4;
        #pragma unroll
        for (int r = 0; r < 4; r++) { HL sp = split2(accO[i][r] * inv); oh4[r] = sp.h; ol4[r] = sp.l; }
        long o = ((long)(b * SEQ + q)) * DIM + h * 64 + i * 16 + l4 * 4;
        *(bf16x4*)&aoh[o] = oh4;
        *(bf16x4*)&aol[o] = ol4;
    }
}

// ---------------- proj split GEMM (glds): C = A@Bt^T + bias + residual -> fp32 ----------------
__global__ __launch_bounds__(256)
void gemm_proj(const bf16* __restrict__ Ah_g, const bf16* __restrict__ Al_g,
               const bf16* __restrict__ Bh_g, const bf16* __restrict__ Bl_g,
               const float* __restrict__ bias, const float* __restrict__ res,
               float* __restrict__ C, int N, int K) {
    __shared__ alignas(16) bf16 Ah[8192], Al[8192], Bh[8192], Bl[8192];
    int tid = threadIdx.x;
    int wave = tid >> 6, lane = tid & 63;
    int l16 = lane & 15, l4 = lane >> 4;
    int wr = (wave >> 1) * 64, wc = (wave & 1) * 64;
    int row0 = blockIdx.y * 128, col0 = blockIdx.x * 128;
    int colb = (lane & 7) * 8;
    f32x4 acc[4][4] = {};
    for (int k0 = 0; k0 < K; k0 += 64) {
        #pragma unroll
        for (int p = 0; p < 4; p++) {
            int rl = p * 32 + wave * 8 + (lane >> 3);
            int lb = p * 2048 + wave * 512;
            gload16(&Ah_g[(long)(row0 + rl) * K + k0 + colb], &Ah[lb]);
            gload16(&Al_g[(long)(row0 + rl) * K + k0 + colb], &Al[lb]);
            gload16(&Bh_g[(long)(col0 + rl) * K + k0 + colb], &Bh[lb]);
            gload16(&Bl_g[(long)(col0 + rl) * K + k0 + colb], &Bl[lb]);
        }
        __syncthreads();
        #pragma unroll
        for (int ks = 0; ks < 2; ks++) {
            bf16x8 ah[4], al[4], bh[4], bl[4];
            #pragma unroll
            for (int i = 0; i < 4; i++) {
                ah[i] = *(const bf16x8*)&Ah[(wr + i*16 + l16)*64 + ks*32 + l4*8];
                al[i] = *(const bf16x8*)&Al[(wr + i*16 + l16)*64 + ks*32 + l4*8];
            }
            #pragma unroll
            for (int j = 0; j < 4; j++) {
                bh[j] = *(const bf16x8*)&Bh[(wc + j*16 + l16)*64 + ks*32 + l4*8];
                bl[j] = *(const bf16x8*)&Bl[(wc + j*16 + l16)*64 + ks*32 + l4*8];
            }
            #pragma unroll
            for (int i = 0; i < 4; i++)
                #pragma unroll
                for (int j = 0; j < 4; j++) {
                    acc[i][j] = __builtin_amdgcn_mfma_f32_16x16x32_bf16(ah[i], bh[j], acc[i][j], 0, 0, 0);
                    acc[i][j] = __builtin_amdgcn_mfma_f32_16x16x32_bf16(ah[i], bl[j], acc[i][j], 0, 0, 0);
                    acc[i][j] = __builtin_amdgcn_mfma_f32_16x16x32_bf16(al[i], bh[j], acc[i][j], 0, 0, 0);
                }
        }
        __syncthreads();
    }
    #pragma unroll
    for (int i = 0; i < 4; i++)
        #pragma unroll
        for (int r = 0; r < 4; r++) {
            int grow = row0 + wr + i * 16 + l4 * 4 + r;
            #pragma unroll
            for (int j = 0; j < 4; j++) {
                int gcol = col0 + wc + j * 16 + l16;
                long o = (long)grow * N + gcol;
                C[o] = acc[i][j][r] + bias[gcol] + res[o];
            }
        }
}

// ---------------- plain bf16 GEMM (glds staging), expert-batched via blockIdx.z ----------------
// OUT_MODE 0: bf16 store; 2: fp32 += v; 3: atomicAdd(Cf[rowmap[row]*N+col], roww[row]*v)
template<bool BIAS, bool GELU, bool GATHER, int OUT_MODE>
__global__ __launch_bounds__(256)
void gemm_bt(const bf16* __restrict__ A, const bf16* __restrict__ Bt,
             const float* __restrict__ bias,
             bf16* __restrict__ Cbf, float* __restrict__ Cf,
             const int* __restrict__ rowmap, const float* __restrict__ roww,
             int M, int N, int K,
             long eA, long eB, long ebias, long eMap, long eC) {
    int ez = blockIdx.z;
    A += (long)ez * eA; Bt += (long)ez * eB;
    if (BIAS) bias += (long)ez * ebias;
    if (GATHER || OUT_MODE == 3) rowmap += (long)ez * eMap;
    if (OUT_MODE == 3) roww += (long)ez * eMap;
    if (OUT_MODE == 0) Cbf += (long)ez * eC;

    __shared__ alignas(16) bf16 As[8192];
    __shared__ alignas(16) bf16 Bs[8192];
    int tid = threadIdx.x;
    int wave = tid >> 6, lane = tid & 63;
    int l16 = lane & 15, l4 = lane >> 4;
    int wr = (wave >> 1) * 64, wc = (wave & 1) * 64;
    int row0 = blockIdx.y * 128, col0 = blockIdx.x * 128;
    int colb = (lane & 7) * 8;

    long arow[4];
    #pragma unroll
    for (int p = 0; p < 4; p++) {
        long gr = row0 + p * 32 + wave * 8 + (lane >> 3);
        if (GATHER) gr = rowmap[gr];
        arow[p] = gr;
    }
    f32x4 acc[4][4] = {};
    for (int k0 = 0; k0 < K; k0 += 64) {
        #pragma unroll
        for (int p = 0; p < 4; p++) {
            int rl = p * 32 + wave * 8 + (lane >> 3);
            int lb = p * 2048 + wave * 512;
            gload16(&A[arow[p] * K + k0 + colb], &As[lb]);
            gload16(&Bt[(long)(col0 + rl) * K + k0 + colb], &Bs[lb]);
        }
        __syncthreads();
        #pragma unroll
        for (int ks = 0; ks < 2; ks++) {
            bf16x8 af[4], bfr[4];
            #pragma unroll
            for (int i = 0; i < 4; i++) af[i]  = *(const bf16x8*)&As[(wr + i*16 + l16)*64 + ks*32 + l4*8];
            #pragma unroll
            for (int j = 0; j < 4; j++) bfr[j] = *(const bf16x8*)&Bs[(wc + j*16 + l16)*64 + ks*32 + l4*8];
            #pragma unroll
            for (int i = 0; i < 4; i++)
                #pragma unroll
                for (int j = 0; j < 4; j++)
                    acc[i][j] = __builtin_amdgcn_mfma_f32_16x16x32_bf16(af[i], bfr[j], acc[i][j], 0, 0, 0);
        }
        __syncthreads();
    }
    #pragma unroll
    for (int i = 0; i < 4; i++)
        #pragma unroll
        for (int r = 0; r < 4; r++) {
            int grow = row0 + wr + i * 16 + l4 * 4 + r;
            int st = 0; float sw = 0.f;
            if (OUT_MODE == 3) { st = rowmap[grow]; sw = roww[grow]; }
            #pragma unroll
            for (int j = 0; j < 4; j++) {
                int gcol = col0 + wc + j * 16 + l16;
                float v = acc[i][j][r];
                if (BIAS) v += bias[gcol];
                if (GELU) v = gelu_exact(v);
                if (OUT_MODE == 0) {
                    Cbf[(long)grow * N + gcol] = (bf16)v;
                } else if (OUT_MODE == 2) {
                    long o = (long)grow * N + gcol;
                    Cf[o] += v;
                } else {
                    atomicAdd(&Cf[(long)st * N + gcol], sw * v);
                }
            }
        }
}

// ---------------- routing (pure fp32, LN inline): one wave per token ----------------
__global__ __launch_bounds__(256)
void routing_kernel(const float* __restrict__ xres, const float* __restrict__ g,
                    const float* __restrict__ b, const float* __restrict__ w_route,
                    const float* __restrict__ b_route, const float* __restrict__ w_noise,
                    const float* __restrict__ b_noise, const float* __restrict__ noise,
                    int* __restrict__ topi, float* __restrict__ topp) {
    int wave = threadIdx.x >> 6, lane = threadIdx.x & 63;
    long t = (long)blockIdx.x * 4 + wave;
    const float* xr = xres + t * DIM;
    float v[16];
    #pragma unroll
    for (int i = 0; i < 16; i++) v[i] = xr[i * 64 + lane];
    float s = 0.f, s2 = 0.f;
    #pragma unroll
    for (int i = 0; i < 16; i++) { s += v[i]; s2 += v[i] * v[i]; }
    #pragma unroll
    for (int m = 1; m < 64; m <<= 1) { s += __shfl_xor(s, m); s2 += __shfl_xor(s2, m); }
    float mu  = s * (1.f / DIM);
    float var = s2 * (1.f / DIM) - mu * mu;
    float rs  = 1.f / sqrtf(var + 1e-5f);
    float accr[4] = {0.f,0.f,0.f,0.f}, accn[4] = {0.f,0.f,0.f,0.f};
    #pragma unroll
    for (int i = 0; i < 16; i++) {
        int d = i * 64 + lane;
        float n = (v[i] - mu) * rs * g[d] + b[d];
        #pragma unroll
        for (int e = 0; e < 4; e++) {
            accr[e] += n * w_route[d * 4 + e];
            accn[e] += n * w_noise[d * 4 + e];
        }
    }
    #pragma unroll
    for (int e = 0; e < 4; e++)
        #pragma unroll
        for (int m = 1; m < 64; m <<= 1) {
            accr[e] += __shfl_xor(accr[e], m);
            accn[e] += __shfl_xor(accn[e], m);
        }
    if (lane == 0) {
        float nz[4];
        #pragma unroll
        for (int e = 0; e < 4; e++) {
            float logit = accr[e] + b_route[e];
            float si = accn[e] + b_noise[e];
            float sp = si > 0.f ? si + log1pf(expf(-si)) : log1pf(expf(si));
            nz[e] = logit + noise[t * 4 + e] * sp;
        }
        int i1 = 0;
        #pragma unroll
        for (int e = 1; e < 4; e++) if (nz[e] > nz[i1]) i1 = e;
        int i2 = -1; float v2 = -1e30f;
        #pragma unroll
        for (int e = 0; e < 4; e++) if (e != i1 && nz[e] > v2) { v2 = nz[e]; i2 = e; }
        float ex = expf(v2 - nz[i1]);
        topi[t * 2]     = i1; topi[t * 2 + 1] = i2;
        topp[t * 2]     = 1.f / (1.f + ex);
        topp[t * 2 + 1] = ex / (1.f + ex);
    }
}

// ---------------- dispatch: per-expert ordered token lists (wave e = expert e) ----------------
__global__ __launch_bounds__(256)
void dispatch_kernel(const int* __restrict__ topi, const float* __restrict__ topp,
                     int* __restrict__ sel, float* __restrict__ wgt) {
    int e = threadIdx.x >> 6, lane = threadIdx.x & 63;
    int cnt = 0;
    for (int c = 0; c < T_TOK; c += 64) {
        int t = c + lane;
        int i0 = topi[t * 2], i1 = topi[t * 2 + 1];
        bool m = (i0 == e) || (i1 == e);
        unsigned long long bal = __ballot(m);
        int pos = cnt + __popcll(bal & ((1ull << lane) - 1ull));
        if (m && pos < CAP) {
            sel[e * CAP + pos] = t;
            wgt[e * CAP + pos] = (i0 == e) ? topp[t * 2] : topp[t * 2 + 1];
        }
        cnt += (int)__popcll(bal);
    }
    if (cnt > CAP) cnt = CAP;
    for (int pos = cnt + lane; pos < CAP; pos += 64) {
        sel[e * CAP + pos] = 0;
        wgt[e * CAP + pos] = 0.f;
    }
}

extern "C" void kernel_launch(void* const* d_in, const int* in_sizes, int n_in,
                              void* d_out, int out_size, void* d_ws, size_t ws_size,
                              hipStream_t stream) {
    (void)in_sizes; (void)n_in; (void)out_size; (void)ws_size;
    const float* x       = (const float*)d_in[0];
    const float* noise   = (const float*)d_in[1];
    const float* ln1_g   = (const float*)d_in[2];
    const float* ln1_b   = (const float*)d_in[3];
    const float* ln2_g   = (const float*)d_in[4];
    const float* ln2_b   = (const float*)d_in[5];
    const float* w_qkv   = (const float*)d_in[6];
    const float* w_proj  = (const float*)d_in[7];
    const float* b_proj  = (const float*)d_in[8];
    const float* w_route = (const float*)d_in[9];
    const float* b_route = (const float*)d_in[10];
    const float* w_noise = (const float*)d_in[11];
    const float* b_noise = (const float*)d_in[12];
    const float* we1     = (const float*)d_in[13];
    const float* be1     = (const float*)d_in[14];
    const float* we2     = (const float*)d_in[15];
    const float* be2     = (const float*)d_in[16];
    const float* w_mlp1  = (const float*)d_in[17];
    const float* b_mlp1  = (const float*)d_in[18];
    const float* w_mlp2  = (const float*)d_in[19];
    const float* b_mlp2  = (const float*)d_in[20];
    float* d_outf = (float*)d_out;

    // ---- workspace (80 MB peak) ----
    const size_t MB = 1024 * 1024;
    char* ws = (char*)d_ws;
    // region A (0..16M): x1h/x1l -> aoh/aol -> w_mlp1T/w_mlp2T
    bf16* x1h = (bf16*)(ws);
    bf16* x1l = (bf16*)(ws + 8 * MB);
    bf16* aoh = (bf16*)(ws);
    bf16* aol = (bf16*)(ws + 8 * MB);
    bf16* w_mlp1T = (bf16*)(ws);
    bf16* w_mlp2T = (bf16*)(ws + 8 * MB);
    // region B (16..28M): wqkvh/wqkvl -> we1T/we2T/h_e
    bf16* wqkvh = (bf16*)(ws + 16 * MB);
    bf16* wqkvl = (bf16*)(ws + 22 * MB);
    bf16* we1T  = (bf16*)(ws + 16 * MB);
    bf16* we2T  = (bf16*)(ws + 18 * MB);
    bf16* h_e   = (bf16*)(ws + 20 * MB);
    // region C (28..32M): wprojh/wprojl
    bf16* wprojh = (bf16*)(ws + 28 * MB);
    bf16* wprojl = (bf16*)(ws + 30 * MB);
    // region D (32..64M): Qh/Ql/Kh/Kl -> h_mlp
    bf16* Qh = (bf16*)(ws + 32 * MB);
    bf16* Ql = (bf16*)(ws + 40 * MB);
    bf16* Kh = (bf16*)(ws + 48 * MB);
    bf16* Kl = (bf16*)(ws + 56 * MB);
    bf16* h_mlp = (bf16*)(ws + 32 * MB);
    // region E (64..80M): VtH/VtL -> x2b + routing buffers
    bf16*  VtH  = (bf16*)(ws + 64 * MB);
    bf16*  VtL  = (bf16*)(ws + 72 * MB);
    bf16*  x2b  = (bf16*)(ws + 64 * MB);
    int*   topi = (int*)(ws + 72 * MB);
    float* topp = (float*)(ws + 72 * MB + 32768);
    int*   sel  = (int*)(ws + 72 * MB + 65536);
    float* wgt  = (float*)(ws + 72 * MB + 98304);

    // ---- phase 1: LN1-split, weight splits ----
    ln_split_kernel<<<T_TOK/4, 256, 0, stream>>>(x, ln1_g, ln1_b, x1h, x1l);
    split_pair_kernel<<<(3*DIM*DIM)/1024, 256, 0, stream>>>(w_qkv, wqkvh, wqkvl);
    split_pair_kernel<<<(DIM*DIM)/1024,   256, 0, stream>>>(w_proj, wprojh, wprojl);

    // ---- phase 2: qkv GEMM (epilogue: Q/K split planes, V split Vt) ----
    gemm_qkv<<<dim3(3*DIM/128, T_TOK/128), 256, 0, stream>>>(
        x1h, x1l, wqkvh, wqkvl, Qh, Ql, Kh, Kl, VtH, VtL);

    // ---- phase 3: flash attention ----
    flash_attn<<<dim3(SEQ/64, 2*NHEAD), 256, 0, stream>>>(Qh, Ql, Kh, Kl, VtH, VtL, aoh, aol);

    // ---- phase 4: proj + bias + residual -> d_out (fp32 stream) ----
    gemm_proj<<<dim3(DIM/128, T_TOK/128), 256, 0, stream>>>(
        aoh, aol, wprojh, wprojl, b_proj, x, d_outf, DIM, DIM);

    // ---- phase 5: LN2 (bf16) + routing + dispatch ----
    ln_kernel<<<T_TOK/4, 256, 0, stream>>>(d_outf, ln2_g, ln2_b, x2b);
    routing_kernel<<<T_TOK/4, 256, 0, stream>>>(d_outf, ln2_g, ln2_b, w_route, b_route,
                                                w_noise, b_noise, noise, topi, topp);
    dispatch_kernel<<<1, 256, 0, stream>>>(topi, topp, sel, wgt);

    // ---- phase 6: weight transposes (aoh/x1 regions dead) ----
    transpose_conv_kernel<<<dim3(MLPH/32, DIM/32, 1),    256, 0, stream>>>(w_mlp1, w_mlp1T, DIM, MLPH);
    transpose_conv_kernel<<<dim3(DIM/32, MLPH/32, 1),    256, 0, stream>>>(w_mlp2, w_mlp2T, MLPH, DIM);
    transpose_conv_kernel<<<dim3(MOEH/32, DIM/32, NEXP), 256, 0, stream>>>(we1, we1T, DIM, MOEH);
    transpose_conv_kernel<<<dim3(DIM/32, MOEH/32, NEXP), 256, 0, stream>>>(we2, we2T, MOEH, DIM);

    // ---- phase 7: dense MLP (mlp2 accumulates into d_out) ----
    gemm_bt<true,true,false,0><<<dim3(MLPH/128, T_TOK/128), 256, 0, stream>>>(
        x2b, w_mlp1T, b_mlp1, h_mlp, nullptr, nullptr, nullptr, T_TOK, MLPH, DIM,
        0, 0, 0, 0, 0);
    gemm_bt<true,false,false,2><<<dim3(DIM/128, T_TOK/128), 256, 0, stream>>>(
        h_mlp, w_mlp2T, b_mlp2, nullptr, d_outf, nullptr, nullptr, T_TOK, DIM, MLPH,
        0, 0, 0, 0, 0);

    // ---- phase 8: MoE experts, batched over blockIdx.z ----
    gemm_bt<true,true,true,0><<<dim3(MOEH/128, CAP/128, NEXP), 256, 0, stream>>>(
        x2b, we1T, be1, h_e, nullptr, sel, nullptr, CAP, MOEH, DIM,
        0, (long)MOEH*DIM, MOEH, CAP, (long)CAP*MOEH);
    gemm_bt<true,false,false,3><<<dim3(DIM/128, CAP/128, NEXP), 256, 0, stream>>>(
        h_e, we2T, be2, nullptr, d_outf, sel, wgt, CAP, DIM, MOEH,
        (long)CAP*MOEH, (long)DIM*MOEH, DIM, CAP, 0);
}

// Round 7
// 739.431 us; speedup vs baseline: 1.4235x; 1.0909x over previous
//
#include <hip/hip_runtime.h>
#include <hip/hip_bf16.h>
#include <math.h>

typedef __bf16 bf16;
typedef __bf16 bf16x4 __attribute__((ext_vector_type(4)));
typedef __bf16 bf16x8 __attribute__((ext_vector_type(8)));
typedef float  f32x4  __attribute__((ext_vector_type(4)));

#define T_TOK 4096
#define DIM   1024
#define NHEAD 16
#define SEQ   2048
#define NEXP  4
#define CAP   2048
#define MLPH  4096
#define MOEH  256

__device__ __forceinline__ float gelu_exact(float v) {
    return 0.5f * v * (1.f + erff(v * 0.70710678118654752f));
}

struct HL { bf16 h, l; };
__device__ __forceinline__ HL split2(float v) {
    HL r; r.h = (bf16)v; r.l = (bf16)(v - (float)r.h); return r;
}

// async global->LDS, 16B per lane; LDS dest = wave-uniform base + lane*16
__device__ __forceinline__ void gload16(const bf16* gptr, bf16* lptr) {
    __builtin_amdgcn_global_load_lds(
        (const __attribute__((address_space(1))) unsigned int*)gptr,
        (__attribute__((address_space(3))) unsigned int*)lptr,
        16, 0, 0);
}

// ---------------- LN1 -> hi/lo bf16 planes: one wave per token ----------------
__global__ __launch_bounds__(256)
void ln_split_kernel(const float* __restrict__ x, const float* __restrict__ g,
                     const float* __restrict__ b, bf16* __restrict__ oh, bf16* __restrict__ ol) {
    int wave = threadIdx.x >> 6, lane = threadIdx.x & 63;
    long t = (long)blockIdx.x * 4 + wave;
    const float* xr = x + t * DIM;
    float v[16];
    #pragma unroll
    for (int i = 0; i < 16; i++) v[i] = xr[i * 64 + lane];
    float s = 0.f, s2 = 0.f;
    #pragma unroll
    for (int i = 0; i < 16; i++) { s += v[i]; s2 += v[i] * v[i]; }
    #pragma unroll
    for (int m = 1; m < 64; m <<= 1) { s += __shfl_xor(s, m); s2 += __shfl_xor(s2, m); }
    float mu  = s * (1.f / DIM);
    float var = s2 * (1.f / DIM) - mu * mu;
    float rs  = 1.f / sqrtf(var + 1e-5f);
    #pragma unroll
    for (int i = 0; i < 16; i++) {
        int d = i * 64 + lane;
        HL sp = split2((v[i] - mu) * rs * g[d] + b[d]);
        oh[t * DIM + d] = sp.h; ol[t * DIM + d] = sp.l;
    }
}

// ---------------- LN (fp32 in -> bf16 out): one wave per token ----------------
__global__ __launch_bounds__(256)
void ln_kernel(const float* __restrict__ x, const float* __restrict__ g,
               const float* __restrict__ b, bf16* __restrict__ out) {
    int wave = threadIdx.x >> 6, lane = threadIdx.x & 63;
    long t = (long)blockIdx.x * 4 + wave;
    const float* xr = x + t * DIM;
    float v[16];
    #pragma unroll
    for (int i = 0; i < 16; i++) v[i] = xr[i * 64 + lane];
    float s = 0.f, s2 = 0.f;
    #pragma unroll
    for (int i = 0; i < 16; i++) { s += v[i]; s2 += v[i] * v[i]; }
    #pragma unroll
    for (int m = 1; m < 64; m <<= 1) { s += __shfl_xor(s, m); s2 += __shfl_xor(s2, m); }
    float mu  = s * (1.f / DIM);
    float var = s2 * (1.f / DIM) - mu * mu;
    float rs  = 1.f / sqrtf(var + 1e-5f);
    #pragma unroll
    for (int i = 0; i < 16; i++) {
        int d = i * 64 + lane;
        out[t * DIM + d] = (bf16)((v[i] - mu) * rs * g[d] + b[d]);
    }
}

// ---------------- elementwise fp32 -> hi/lo planes ----------------
__global__ __launch_bounds__(256)
void split_pair_kernel(const float* __restrict__ in, bf16* __restrict__ h, bf16* __restrict__ l) {
    long i0 = ((long)blockIdx.x * 256 + threadIdx.x) * 4;
    f32x4 v = *(const f32x4*)&in[i0];
    bf16x4 vh, vl;
    #pragma unroll
    for (int j = 0; j < 4; j++) { HL sp = split2(v[j]); vh[j] = sp.h; vl[j] = sp.l; }
    *(bf16x4*)&h[i0] = vh; *(bf16x4*)&l[i0] = vl;
}

// ---------------- transpose fp32 -> bf16 (32x32 tiles, batched in z) ----------------
__global__ __launch_bounds__(256)
void transpose_conv_kernel(const float* __restrict__ in, bf16* __restrict__ out, int R, int C) {
    __shared__ bf16 tile[32][33];
    long bo = (long)blockIdx.z * R * C;
    in += bo; out += bo;
    int c0 = blockIdx.x * 32, r0 = blockIdx.y * 32;
    int tx = threadIdx.x & 31, ty = threadIdx.x >> 5;
    #pragma unroll
    for (int i = 0; i < 32; i += 8)
        tile[ty + i][tx] = (bf16)in[(long)(r0 + ty + i) * C + c0 + tx];
    __syncthreads();
    #pragma unroll
    for (int i = 0; i < 32; i += 8)
        out[(long)(c0 + ty + i) * R + r0 + tx] = tile[tx][ty + i];
}

// ---------------- qkv split GEMM: glds staging; epilogue -> Q(pre-scaled)/K split planes + split Vt ----------------
__global__ __launch_bounds__(256)
void gemm_qkv(const bf16* __restrict__ Ah_g, const bf16* __restrict__ Al_g,
              const bf16* __restrict__ Bh_g, const bf16* __restrict__ Bl_g,
              bf16* __restrict__ Qh_g, bf16* __restrict__ Ql_g,
              bf16* __restrict__ Kh_g, bf16* __restrict__ Kl_g,
              bf16* __restrict__ VtH, bf16* __restrict__ VtL) {
    const int K = DIM;
    __shared__ alignas(16) bf16 Ah[8192], Al[8192], Bh[8192], Bl[8192];
    int tid = threadIdx.x;
    int wave = tid >> 6, lane = tid & 63;
    int l16 = lane & 15, l4 = lane >> 4;
    int wr = (wave >> 1) * 64, wc = (wave & 1) * 64;
    int row0 = blockIdx.y * 128, col0 = blockIdx.x * 128;
    int colb = (lane & 7) * 8;
    f32x4 acc[4][4] = {};
    for (int k0 = 0; k0 < K; k0 += 64) {
        #pragma unroll
        for (int p = 0; p < 4; p++) {
            int rl = p * 32 + wave * 8 + (lane >> 3);
            int lb = p * 2048 + wave * 512;
            gload16(&Ah_g[(long)(row0 + rl) * K + k0 + colb], &Ah[lb]);
            gload16(&Al_g[(long)(row0 + rl) * K + k0 + colb], &Al[lb]);
            gload16(&Bh_g[(long)(col0 + rl) * K + k0 + colb], &Bh[lb]);
            gload16(&Bl_g[(long)(col0 + rl) * K + k0 + colb], &Bl[lb]);
        }
        __syncthreads();
        #pragma unroll
        for (int ks = 0; ks < 2; ks++) {
            bf16x8 ah[4], al[4], bh[4], bl[4];
            #pragma unroll
            for (int i = 0; i < 4; i++) {
                ah[i] = *(const bf16x8*)&Ah[(wr + i*16 + l16)*64 + ks*32 + l4*8];
                al[i] = *(const bf16x8*)&Al[(wr + i*16 + l16)*64 + ks*32 + l4*8];
            }
            #pragma unroll
            for (int j = 0; j < 4; j++) {
                bh[j] = *(const bf16x8*)&Bh[(wc + j*16 + l16)*64 + ks*32 + l4*8];
                bl[j] = *(const bf16x8*)&Bl[(wc + j*16 + l16)*64 + ks*32 + l4*8];
            }
            #pragma unroll
            for (int i = 0; i < 4; i++)
                #pragma unroll
                for (int j = 0; j < 4; j++) {
                    acc[i][j] = __builtin_amdgcn_mfma_f32_16x16x32_bf16(ah[i], bh[j], acc[i][j], 0, 0, 0);
                    acc[i][j] = __builtin_amdgcn_mfma_f32_16x16x32_bf16(ah[i], bl[j], acc[i][j], 0, 0, 0);
                    acc[i][j] = __builtin_amdgcn_mfma_f32_16x16x32_bf16(al[i], bh[j], acc[i][j], 0, 0, 0);
                }
        }
        __syncthreads();
    }
    if (col0 < 2048) {   // Q/K columns -> split planes [bh][s][64]; Q pre-scaled by 1/8 (exact)
        bf16* oh = (col0 < 1024) ? Qh_g : Kh_g;
        bf16* ol = (col0 < 1024) ? Ql_g : Kl_g;
        float qscale = (col0 < 1024) ? 0.125f : 1.0f;
        #pragma unroll
        for (int i = 0; i < 4; i++)
            #pragma unroll
            for (int r = 0; r < 4; r++) {
                int t = row0 + wr + i * 16 + l4 * 4 + r;
                int bq = t >> 11, s = t & 2047;
                #pragma unroll
                for (int j = 0; j < 4; j++) {
                    int col = (col0 + wc + j * 16 + l16) & 1023;
                    int hh = col >> 6, dl = col & 63;
                    long o = ((long)(bq * NHEAD + hh) * SEQ + s) * 64 + dl;
                    HL sp = split2(acc[i][j][r] * qscale);
                    oh[o] = sp.h; ol[o] = sp.l;
                }
            }
    } else {             // V columns -> split + transposed Vt[bh][d][s], r-packed b64 stores
        #pragma unroll
        for (int i = 0; i < 4; i++) {
            int s0 = row0 + wr + i * 16 + l4 * 4;
            int b = s0 >> 11, sl = s0 & 2047;
            #pragma unroll
            for (int j = 0; j < 4; j++) {
                int d = col0 - 2048 + wc + j * 16 + l16;
                int h = d >> 6, dl = d & 63;
                long base = ((long)(b * NHEAD + h) * 64 + dl) * SEQ + sl;
                bf16x4 vh, vl;
                #pragma unroll
                for (int r = 0; r < 4; r++) { HL sp = split2(acc[i][j][r]); vh[r] = sp.h; vl[r] = sp.l; }
                *(bf16x4*)&VtH[base] = vh;
                *(bf16x4*)&VtL[base] = vl;
            }
        }
    }
}

// swizzled fragment read: logical (row, 16B-chunk cc) stored at chunk cc^(row&7)
__device__ __forceinline__ bf16x8 sw_frag(const bf16* arr, int row, int cc) {
    return *(const bf16x8*)&arr[row * 64 + ((cc ^ (row & 7)) * 8)];
}

// ---------------- flash attention: S^T orientation, swizzled K/V staging, Q in registers ----------------
__global__ __launch_bounds__(256)
void flash_attn(const bf16* __restrict__ Qh_g, const bf16* __restrict__ Ql_g,
                const bf16* __restrict__ Kh_g, const bf16* __restrict__ Kl_g,
                const bf16* __restrict__ VtH_g, const bf16* __restrict__ VtL_g,
                bf16* __restrict__ aoh, bf16* __restrict__ aol) {
    __shared__ alignas(16) bf16 Kh[4096], Kl[4096], Vth[4096], Vtl[4096];
    __shared__ alignas(16) bf16 Pth[4][16][72], Ptl[4][16][72];
    int tid = threadIdx.x;
    int wave = tid >> 6, lane = tid & 63;
    int l16 = lane & 15, l4 = lane >> 4;
    int bid = blockIdx.x;
    int bh = bid & 31;            // same-bh blocks share XCD (bid%8 == bh%8) -> K/V stay in that L2
    int b = bh >> 4, h = bh & 15;
    int q0 = (bid >> 5) * 64;

    // Q fragments (pre-scaled by 1/8 at producer) straight into registers
    bf16x8 qfh[2], qfl[2];
    {
        const bf16* qh = Qh_g + ((long)bh * SEQ + q0 + wave * 16 + l16) * 64;
        const bf16* ql = Ql_g + ((long)bh * SEQ + q0 + wave * 16 + l16) * 64;
        #pragma unroll
        for (int ks = 0; ks < 2; ks++) {
            qfh[ks] = *(const bf16x8*)&qh[ks * 32 + l4 * 8];
            qfl[ks] = *(const bf16x8*)&ql[ks * 32 + l4 * 8];
        }
    }
    int r8 = lane >> 3;
    int swc = ((lane & 7) ^ r8) * 8;   // swizzled 16B chunk within the row
    float m_s = -1e30f, l_s = 0.f;
    f32x4 accO[4] = {};

    for (int c0 = 0; c0 < SEQ; c0 += 64) {
        __syncthreads();   // prev iter's LDS reads done; drains outstanding glds
        {
            const bf16* kh = Kh_g + ((long)bh * SEQ + c0) * 64;
            const bf16* kl = Kl_g + ((long)bh * SEQ + c0) * 64;
            const bf16* vh = VtH_g + (long)bh * 64 * SEQ + c0;
            const bf16* vl = VtL_g + (long)bh * 64 * SEQ + c0;
            #pragma unroll
            for (int p = 0; p < 2; p++) {
                int R0 = wave * 16 + p * 8;           // 8-row group
                int row = R0 + r8;
                gload16(&kh[(long)row * 64 + swc], &Kh[R0 * 64]);
                gload16(&kl[(long)row * 64 + swc], &Kl[R0 * 64]);
                gload16(&vh[(long)row * SEQ + swc], &Vth[R0 * 64]);
                gload16(&vl[(long)row * SEQ + swc], &Vtl[R0 * 64]);
            }
        }
        __syncthreads();
        // S^T[key][q] = K Q^T for keys [0,64), q-cols [wave*16, +16)
        f32x4 st[4] = {};
        #pragma unroll
        for (int ks = 0; ks < 2; ks++) {
            #pragma unroll
            for (int i = 0; i < 4; i++) {
                bf16x8 akh = sw_frag(Kh, i * 16 + l16, ks * 4 + l4);
                bf16x8 akl = sw_frag(Kl, i * 16 + l16, ks * 4 + l4);
                st[i] = __builtin_amdgcn_mfma_f32_16x16x32_bf16(akh, qfh[ks], st[i], 0, 0, 0);
                st[i] = __builtin_amdgcn_mfma_f32_16x16x32_bf16(akl, qfh[ks], st[i], 0, 0, 0);
                st[i] = __builtin_amdgcn_mfma_f32_16x16x32_bf16(akh, qfl[ks], st[i], 0, 0, 0);
            }
        }
        // online softmax over this lane's q-column (16 keys in-reg + 2 shuffles over l4)
        float mx = st[0][0];
        #pragma unroll
        for (int i = 0; i < 4; i++)
            #pragma unroll
            for (int r = 0; r < 4; r++) mx = fmaxf(mx, st[i][r]);
        mx = fmaxf(mx, __shfl_xor(mx, 16));
        mx = fmaxf(mx, __shfl_xor(mx, 32));
        float mnew = fmaxf(m_s, mx);
        float alpha = expf(m_s - mnew);
        float psum = 0.f;
        #pragma unroll
        for (int i = 0; i < 4; i++)
            #pragma unroll
            for (int r = 0; r < 4; r++) {
                float pv = expf(st[i][r] - mnew);
                st[i][r] = pv; psum += pv;
            }
        psum += __shfl_xor(psum, 16);
        psum += __shfl_xor(psum, 32);
        l_s = l_s * alpha + psum;
        m_s = mnew;
        #pragma unroll
        for (int i = 0; i < 4; i++)
            #pragma unroll
            for (int r = 0; r < 4; r++) accO[i][r] *= alpha;
        // P^T -> Pt[wave][q][s] (r-contiguous b64 stores, padded rows)
        #pragma unroll
        for (int i = 0; i < 4; i++) {
            bf16x4 ph, pl;
            #pragma unroll
            for (int r = 0; r < 4; r++) { HL sp = split2(st[i][r]); ph[r] = sp.h; pl[r] = sp.l; }
            *(bf16x4*)&Pth[wave][l16][i * 16 + l4 * 4] = ph;
            *(bf16x4*)&Ptl[wave][l16][i * 16 + l4 * 4] = pl;
        }
        // O^T += Vt @ P^T
        #pragma unroll
        for (int ks = 0; ks < 2; ks++) {
            bf16x8 bph = *(const bf16x8*)&Pth[wave][l16][ks * 32 + l4 * 8];
            bf16x8 bpl = *(const bf16x8*)&Ptl[wave][l16][ks * 32 + l4 * 8];
            #pragma unroll
            for (int i = 0; i < 4; i++) {
                bf16x8 avh = sw_frag(Vth, i * 16 + l16, ks * 4 + l4);
                bf16x8 avl = sw_frag(Vtl, i * 16 + l16, ks * 4 + l4);
                accO[i] = __builtin_amdgcn_mfma_f32_16x16x32_bf16(avh, bph, accO[i], 0, 0, 0);
                accO[i] = __builtin_amdgcn_mfma_f32_16x16x32_bf16(avh, bpl, accO[i], 0, 0, 0);
                accO[i] = __builtin_amdgcn_mfma_f32_16x16x32_bf16(avl, bph, accO[i], 0, 0, 0);
            }
        }
    }
    // epilogue: lane owns q = q0 + wave*16 + l16; d = i*16 + l4*4 + r -> b64 packed
    float inv = 1.f / l_s;
    int q = q0 + wave * 16 + l16;
    #pragma unroll
    for (int i = 0; i < 4; i++) {
        bf16x4 oh4, ol4;
        #pragma unroll
        for (int r = 0; r < 4; r++) { HL sp = split2(accO[i][r] * inv); oh4[r] = sp.h; ol4[r] = sp.l; }
        long o = ((long)(b * SEQ + q)) * DIM + h * 64 + i * 16 + l4 * 4;
        *(bf16x4*)&aoh[o] = oh4;
        *(bf16x4*)&aol[o] = ol4;
    }
}

// ---------------- proj split GEMM (glds): C = A@Bt^T + bias + residual -> fp32 ----------------
__global__ __launch_bounds__(256)
void gemm_proj(const bf16* __restrict__ Ah_g, const bf16* __restrict__ Al_g,
               const bf16* __restrict__ Bh_g, const bf16* __restrict__ Bl_g,
               const float* __restrict__ bias, const float* __restrict__ res,
               float* __restrict__ C, int N, int K) {
    __shared__ alignas(16) bf16 Ah[8192], Al[8192], Bh[8192], Bl[8192];
    int tid = threadIdx.x;
    int wave = tid >> 6, lane = tid & 63;
    int l16 = lane & 15, l4 = lane >> 4;
    int wr = (wave >> 1) * 64, wc = (wave & 1) * 64;
    int row0 = blockIdx.y * 128, col0 = blockIdx.x * 128;
    int colb = (lane & 7) * 8;
    f32x4 acc[4][4] = {};
    for (int k0 = 0; k0 < K; k0 += 64) {
        #pragma unroll
        for (int p = 0; p < 4; p++) {
            int rl = p * 32 + wave * 8 + (lane >> 3);
            int lb = p * 2048 + wave * 512;
            gload16(&Ah_g[(long)(row0 + rl) * K + k0 + colb], &Ah[lb]);
            gload16(&Al_g[(long)(row0 + rl) * K + k0 + colb], &Al[lb]);
            gload16(&Bh_g[(long)(col0 + rl) * K + k0 + colb], &Bh[lb]);
            gload16(&Bl_g[(long)(col0 + rl) * K + k0 + colb], &Bl[lb]);
        }
        __syncthreads();
        #pragma unroll
        for (int ks = 0; ks < 2; ks++) {
            bf16x8 ah[4], al[4], bh[4], bl[4];
            #pragma unroll
            for (int i = 0; i < 4; i++) {
                ah[i] = *(const bf16x8*)&Ah[(wr + i*16 + l16)*64 + ks*32 + l4*8];
                al[i] = *(const bf16x8*)&Al[(wr + i*16 + l16)*64 + ks*32 + l4*8];
            }
            #pragma unroll
            for (int j = 0; j < 4; j++) {
                bh[j] = *(const bf16x8*)&Bh[(wc + j*16 + l16)*64 + ks*32 + l4*8];
                bl[j] = *(const bf16x8*)&Bl[(wc + j*16 + l16)*64 + ks*32 + l4*8];
            }
            #pragma unroll
            for (int i = 0; i < 4; i++)
                #pragma unroll
                for (int j = 0; j < 4; j++) {
                    acc[i][j] = __builtin_amdgcn_mfma_f32_16x16x32_bf16(ah[i], bh[j], acc[i][j], 0, 0, 0);
                    acc[i][j] = __builtin_amdgcn_mfma_f32_16x16x32_bf16(ah[i], bl[j], acc[i][j], 0, 0, 0);
                    acc[i][j] = __builtin_amdgcn_mfma_f32_16x16x32_bf16(al[i], bh[j], acc[i][j], 0, 0, 0);
                }
        }
        __syncthreads();
    }
    #pragma unroll
    for (int i = 0; i < 4; i++)
        #pragma unroll
        for (int r = 0; r < 4; r++) {
            int grow = row0 + wr + i * 16 + l4 * 4 + r;
            #pragma unroll
            for (int j = 0; j < 4; j++) {
                int gcol = col0 + wc + j * 16 + l16;
                long o = (long)grow * N + gcol;
                C[o] = acc[i][j][r] + bias[gcol] + res[o];
            }
        }
}

// ---------------- plain bf16 GEMM (glds staging), expert-batched via blockIdx.z ----------------
// OUT_MODE 0: bf16 store; 2: fp32 += v; 3: atomicAdd(Cf[rowmap[row]*N+col], roww[row]*v)
template<bool BIAS, bool GELU, bool GATHER, int OUT_MODE>
__global__ __launch_bounds__(256)
void gemm_bt(const bf16* __restrict__ A, const bf16* __restrict__ Bt,
             const float* __restrict__ bias,
             bf16* __restrict__ Cbf, float* __restrict__ Cf,
             const int* __restrict__ rowmap, const float* __restrict__ roww,
             int M, int N, int K,
             long eA, long eB, long ebias, long eMap, long eC) {
    int ez = blockIdx.z;
    A += (long)ez * eA; Bt += (long)ez * eB;
    if (BIAS) bias += (long)ez * ebias;
    if (GATHER || OUT_MODE == 3) rowmap += (long)ez * eMap;
    if (OUT_MODE == 3) roww += (long)ez * eMap;
    if (OUT_MODE == 0) Cbf += (long)ez * eC;

    __shared__ alignas(16) bf16 As[8192];
    __shared__ alignas(16) bf16 Bs[8192];
    int tid = threadIdx.x;
    int wave = tid >> 6, lane = tid & 63;
    int l16 = lane & 15, l4 = lane >> 4;
    int wr = (wave >> 1) * 64, wc = (wave & 1) * 64;
    int row0 = blockIdx.y * 128, col0 = blockIdx.x * 128;
    int colb = (lane & 7) * 8;

    long arow[4];
    #pragma unroll
    for (int p = 0; p < 4; p++) {
        long gr = row0 + p * 32 + wave * 8 + (lane >> 3);
        if (GATHER) gr = rowmap[gr];
        arow[p] = gr;
    }
    f32x4 acc[4][4] = {};
    for (int k0 = 0; k0 < K; k0 += 64) {
        #pragma unroll
        for (int p = 0; p < 4; p++) {
            int rl = p * 32 + wave * 8 + (lane >> 3);
            int lb = p * 2048 + wave * 512;
            gload16(&A[arow[p] * K + k0 + colb], &As[lb]);
            gload16(&Bt[(long)(col0 + rl) * K + k0 + colb], &Bs[lb]);
        }
        __syncthreads();
        #pragma unroll
        for (int ks = 0; ks < 2; ks++) {
            bf16x8 af[4], bfr[4];
            #pragma unroll
            for (int i = 0; i < 4; i++) af[i]  = *(const bf16x8*)&As[(wr + i*16 + l16)*64 + ks*32 + l4*8];
            #pragma unroll
            for (int j = 0; j < 4; j++) bfr[j] = *(const bf16x8*)&Bs[(wc + j*16 + l16)*64 + ks*32 + l4*8];
            #pragma unroll
            for (int i = 0; i < 4; i++)
                #pragma unroll
                for (int j = 0; j < 4; j++)
                    acc[i][j] = __builtin_amdgcn_mfma_f32_16x16x32_bf16(af[i], bfr[j], acc[i][j], 0, 0, 0);
        }
        __syncthreads();
    }
    #pragma unroll
    for (int i = 0; i < 4; i++)
        #pragma unroll
        for (int r = 0; r < 4; r++) {
            int grow = row0 + wr + i * 16 + l4 * 4 + r;
            int st = 0; float sw = 0.f;
            if (OUT_MODE == 3) { st = rowmap[grow]; sw = roww[grow]; }
            #pragma unroll
            for (int j = 0; j < 4; j++) {
                int gcol = col0 + wc + j * 16 + l16;
                float v = acc[i][j][r];
                if (BIAS) v += bias[gcol];
                if (GELU) v = gelu_exact(v);
                if (OUT_MODE == 0) {
                    Cbf[(long)grow * N + gcol] = (bf16)v;
                } else if (OUT_MODE == 2) {
                    long o = (long)grow * N + gcol;
                    Cf[o] += v;
                } else {
                    atomicAdd(&Cf[(long)st * N + gcol], sw * v);
                }
            }
        }
}

// ---------------- routing (pure fp32, LN inline): one wave per token ----------------
__global__ __launch_bounds__(256)
void routing_kernel(const float* __restrict__ xres, const float* __restrict__ g,
                    const float* __restrict__ b, const float* __restrict__ w_route,
                    const float* __restrict__ b_route, const float* __restrict__ w_noise,
                    const float* __restrict__ b_noise, const float* __restrict__ noise,
                    int* __restrict__ topi, float* __restrict__ topp) {
    int wave = threadIdx.x >> 6, lane = threadIdx.x & 63;
    long t = (long)blockIdx.x * 4 + wave;
    const float* xr = xres + t * DIM;
    float v[16];
    #pragma unroll
    for (int i = 0; i < 16; i++) v[i] = xr[i * 64 + lane];
    float s = 0.f, s2 = 0.f;
    #pragma unroll
    for (int i = 0; i < 16; i++) { s += v[i]; s2 += v[i] * v[i]; }
    #pragma unroll
    for (int m = 1; m < 64; m <<= 1) { s += __shfl_xor(s, m); s2 += __shfl_xor(s2, m); }
    float mu  = s * (1.f / DIM);
    float var = s2 * (1.f / DIM) - mu * mu;
    float rs  = 1.f / sqrtf(var + 1e-5f);
    float accr[4] = {0.f,0.f,0.f,0.f}, accn[4] = {0.f,0.f,0.f,0.f};
    #pragma unroll
    for (int i = 0; i < 16; i++) {
        int d = i * 64 + lane;
        float n = (v[i] - mu) * rs * g[d] + b[d];
        #pragma unroll
        for (int e = 0; e < 4; e++) {
            accr[e] += n * w_route[d * 4 + e];
            accn[e] += n * w_noise[d * 4 + e];
        }
    }
    #pragma unroll
    for (int e = 0; e < 4; e++)
        #pragma unroll
        for (int m = 1; m < 64; m <<= 1) {
            accr[e] += __shfl_xor(accr[e], m);
            accn[e] += __shfl_xor(accn[e], m);
        }
    if (lane == 0) {
        float nz[4];
        #pragma unroll
        for (int e = 0; e < 4; e++) {
            float logit = accr[e] + b_route[e];
            float si = accn[e] + b_noise[e];
            float sp = si > 0.f ? si + log1pf(expf(-si)) : log1pf(expf(si));
            nz[e] = logit + noise[t * 4 + e] * sp;
        }
        int i1 = 0;
        #pragma unroll
        for (int e = 1; e < 4; e++) if (nz[e] > nz[i1]) i1 = e;
        int i2 = -1; float v2 = -1e30f;
        #pragma unroll
        for (int e = 0; e < 4; e++) if (e != i1 && nz[e] > v2) { v2 = nz[e]; i2 = e; }
        float ex = expf(v2 - nz[i1]);
        topi[t * 2]     = i1; topi[t * 2 + 1] = i2;
        topp[t * 2]     = 1.f / (1.f + ex);
        topp[t * 2 + 1] = ex / (1.f + ex);
    }
}

// ---------------- dispatch: per-expert ordered token lists (wave e = expert e) ----------------
__global__ __launch_bounds__(256)
void dispatch_kernel(const int* __restrict__ topi, const float* __restrict__ topp,
                     int* __restrict__ sel, float* __restrict__ wgt) {
    int e = threadIdx.x >> 6, lane = threadIdx.x & 63;
    int cnt = 0;
    for (int c = 0; c < T_TOK; c += 64) {
        int t = c + lane;
        int i0 = topi[t * 2], i1 = topi[t * 2 + 1];
        bool m = (i0 == e) || (i1 == e);
        unsigned long long bal = __ballot(m);
        int pos = cnt + __popcll(bal & ((1ull << lane) - 1ull));
        if (m && pos < CAP) {
            sel[e * CAP + pos] = t;
            wgt[e * CAP + pos] = (i0 == e) ? topp[t * 2] : topp[t * 2 + 1];
        }
        cnt += (int)__popcll(bal);
    }
    if (cnt > CAP) cnt = CAP;
    for (int pos = cnt + lane; pos < CAP; pos += 64) {
        sel[e * CAP + pos] = 0;
        wgt[e * CAP + pos] = 0.f;
    }
}

extern "C" void kernel_launch(void* const* d_in, const int* in_sizes, int n_in,
                              void* d_out, int out_size, void* d_ws, size_t ws_size,
                              hipStream_t stream) {
    (void)in_sizes; (void)n_in; (void)out_size; (void)ws_size;
    const float* x       = (const float*)d_in[0];
    const float* noise   = (const float*)d_in[1];
    const float* ln1_g   = (const float*)d_in[2];
    const float* ln1_b   = (const float*)d_in[3];
    const float* ln2_g   = (const float*)d_in[4];
    const float* ln2_b   = (const float*)d_in[5];
    const float* w_qkv   = (const float*)d_in[6];
    const float* w_proj  = (const float*)d_in[7];
    const float* b_proj  = (const float*)d_in[8];
    const float* w_route = (const float*)d_in[9];
    const float* b_route = (const float*)d_in[10];
    const float* w_noise = (const float*)d_in[11];
    const float* b_noise = (const float*)d_in[12];
    const float* we1     = (const float*)d_in[13];
    const float* be1     = (const float*)d_in[14];
    const float* we2     = (const float*)d_in[15];
    const float* be2     = (const float*)d_in[16];
    const float* w_mlp1  = (const float*)d_in[17];
    const float* b_mlp1  = (const float*)d_in[18];
    const float* w_mlp2  = (const float*)d_in[19];
    const float* b_mlp2  = (const float*)d_in[20];
    float* d_outf = (float*)d_out;

    // ---- workspace (80 MB peak) ----
    const size_t MB = 1024 * 1024;
    char* ws = (char*)d_ws;
    // region A (0..16M): x1h/x1l -> aoh/aol -> w_mlp1T/w_mlp2T
    bf16* x1h = (bf16*)(ws);
    bf16* x1l = (bf16*)(ws + 8 * MB);
    bf16* aoh = (bf16*)(ws);
    bf16* aol = (bf16*)(ws + 8 * MB);
    bf16* w_mlp1T = (bf16*)(ws);
    bf16* w_mlp2T = (bf16*)(ws + 8 * MB);
    // region B (16..28M): wqkvh/wqkvl -> we1T/we2T/h_e
    bf16* wqkvh = (bf16*)(ws + 16 * MB);
    bf16* wqkvl = (bf16*)(ws + 22 * MB);
    bf16* we1T  = (bf16*)(ws + 16 * MB);
    bf16* we2T  = (bf16*)(ws + 18 * MB);
    bf16* h_e   = (bf16*)(ws + 20 * MB);
    // region C (28..32M): wprojh/wprojl
    bf16* wprojh = (bf16*)(ws + 28 * MB);
    bf16* wprojl = (bf16*)(ws + 30 * MB);
    // region D (32..64M): Qh/Ql/Kh/Kl -> h_mlp
    bf16* Qh = (bf16*)(ws + 32 * MB);
    bf16* Ql = (bf16*)(ws + 40 * MB);
    bf16* Kh = (bf16*)(ws + 48 * MB);
    bf16* Kl = (bf16*)(ws + 56 * MB);
    bf16* h_mlp = (bf16*)(ws + 32 * MB);
    // region E (64..80M): VtH/VtL -> x2b + routing buffers
    bf16*  VtH  = (bf16*)(ws + 64 * MB);
    bf16*  VtL  = (bf16*)(ws + 72 * MB);
    bf16*  x2b  = (bf16*)(ws + 64 * MB);
    int*   topi = (int*)(ws + 72 * MB);
    float* topp = (float*)(ws + 72 * MB + 32768);
    int*   sel  = (int*)(ws + 72 * MB + 65536);
    float* wgt  = (float*)(ws + 72 * MB + 98304);

    // ---- phase 1: LN1-split, weight splits ----
    ln_split_kernel<<<T_TOK/4, 256, 0, stream>>>(x, ln1_g, ln1_b, x1h, x1l);
    split_pair_kernel<<<(3*DIM*DIM)/1024, 256, 0, stream>>>(w_qkv, wqkvh, wqkvl);
    split_pair_kernel<<<(DIM*DIM)/1024,   256, 0, stream>>>(w_proj, wprojh, wprojl);

    // ---- phase 2: qkv GEMM (epilogue: Q(x0.125)/K split planes, V split Vt) ----
    gemm_qkv<<<dim3(3*DIM/128, T_TOK/128), 256, 0, stream>>>(
        x1h, x1l, wqkvh, wqkvl, Qh, Ql, Kh, Kl, VtH, VtL);

    // ---- phase 3: flash attention (1-D grid: bid&31 = bh -> XCD locality) ----
    flash_attn<<<dim3(32 * (SEQ/64)), 256, 0, stream>>>(Qh, Ql, Kh, Kl, VtH, VtL, aoh, aol);

    // ---- phase 4: proj + bias + residual -> d_out (fp32 stream) ----
    gemm_proj<<<dim3(DIM/128, T_TOK/128), 256, 0, stream>>>(
        aoh, aol, wprojh, wprojl, b_proj, x, d_outf, DIM, DIM);

    // ---- phase 5: LN2 (bf16) + routing + dispatch ----
    ln_kernel<<<T_TOK/4, 256, 0, stream>>>(d_outf, ln2_g, ln2_b, x2b);
    routing_kernel<<<T_TOK/4, 256, 0, stream>>>(d_outf, ln2_g, ln2_b, w_route, b_route,
                                                w_noise, b_noise, noise, topi, topp);
    dispatch_kernel<<<1, 256, 0, stream>>>(topi, topp, sel, wgt);

    // ---- phase 6: weight transposes (aoh/x1 regions dead) ----
    transpose_conv_kernel<<<dim3(MLPH/32, DIM/32, 1),    256, 0, stream>>>(w_mlp1, w_mlp1T, DIM, MLPH);
    transpose_conv_kernel<<<dim3(DIM/32, MLPH/32, 1),    256, 0, stream>>>(w_mlp2, w_mlp2T, MLPH, DIM);
    transpose_conv_kernel<<<dim3(MOEH/32, DIM/32, NEXP), 256, 0, stream>>>(we1, we1T, DIM, MOEH);
    transpose_conv_kernel<<<dim3(DIM/32, MOEH/32, NEXP), 256, 0, stream>>>(we2, we2T, MOEH, DIM);

    // ---- phase 7: dense MLP (mlp2 accumulates into d_out) ----
    gemm_bt<true,true,false,0><<<dim3(MLPH/128, T_TOK/128), 256, 0, stream>>>(
        x2b, w_mlp1T, b_mlp1, h_mlp, nullptr, nullptr, nullptr, T_TOK, MLPH, DIM,
        0, 0, 0, 0, 0);
    gemm_bt<true,false,false,2><<<dim3(DIM/128, T_TOK/128), 256, 0, stream>>>(
        h_mlp, w_mlp2T, b_mlp2, nullptr, d_outf, nullptr, nullptr, T_TOK, DIM, MLPH,
        0, 0, 0, 0, 0);

    // ---- phase 8: MoE experts, batched over blockIdx.z ----
    gemm_bt<true,true,true,0><<<dim3(MOEH/128, CAP/128, NEXP), 256, 0, stream>>>(
        x2b, we1T, be1, h_e, nullptr, sel, nullptr, CAP, MOEH, DIM,
        0, (long)MOEH*DIM, MOEH, CAP, (long)CAP*MOEH);
    gemm_bt<true,false,false,3><<<dim3(DIM/128, CAP/128, NEXP), 256, 0, stream>>>(
        h_e, we2T, be2, nullptr, d_outf, sel, wgt, CAP, DIM, MOEH,
        (long)CAP*MOEH, (long)DIM*MOEH, DIM, CAP, 0);
}